// Round 1
// baseline (722.837 us; speedup 1.0000x reference)
//
#include <hip/hip_runtime.h>
#include <hip/hip_bf16.h>
#include <math.h>

// Problem constants (SingleHyperTKAN)
#define BB 8
#define TT 24
#define NN 1000
#define EE 1000
#define DEG 20
#define FIN 16
#define CRAW 8
#define DM 32
#define HCN 32
#define TKN 32
#define PREDN 12
#define LAMF 0.3f
#define EPSF 1e-8f

// ws budget (floats): zx 24,576,000 | z 6,144,000 | v 6,144,000 | feat 128,000
// | Wd 8,000 | dvi 8,000 | ints 46,002  => ~148.3 MB total

__device__ __forceinline__ float sigmoidf_(float x){ return 1.f/(1.f+__expf(-x)); }
__device__ __forceinline__ float siluf_(float x){ return x/(1.f+__expf(-x)); }

// ---------------- feat: mean/std over T ----------------
__global__ void k_feat(const float* __restrict__ xraw, float* __restrict__ feat){
  int idx = blockIdx.x*blockDim.x + threadIdx.x; // (b*N+n)
  if (idx >= BB*NN) return;
  int b = idx/NN, n = idx%NN;
  float s[8], s2[8];
  #pragma unroll
  for(int c=0;c<8;c++){ s[c]=0.f; s2[c]=0.f; }
  for (int t=0;t<TT;t++){
    const float* p = xraw + (((size_t)(b*TT+t)*NN + n)*CRAW);
    #pragma unroll
    for (int c=0;c<8;c++){ float v=p[c]; s[c]+=v; s2[c]+=v*v; }
  }
  float* f = feat + (size_t)idx*16;
  #pragma unroll
  for (int c=0;c<8;c++){
    float m = s[c]*(1.f/TT);
    float var = fmaxf(s2[c]*(1.f/TT) - m*m, 0.f);
    f[c] = m; f[8+c] = sqrtf(var);
  }
}

// ---------------- edge dedup + De + node degree counts ----------------
__global__ void k_edges(const int* __restrict__ members, const int* __restrict__ centers,
                        const int* __restrict__ offsets,
                        int* __restrict__ edge_nodes, int* __restrict__ edge_cnt,
                        int* __restrict__ node_deg){
  int e = blockIdx.x*blockDim.x + threadIdx.x;
  if (e>=EE) return;
  int st = offsets[e], en = offsets[e+1];
  int list[DEG+1]; int cnt=0;
  list[cnt++] = centers[e];
  for (int k=st;k<en;k++){
    int m = members[k];
    bool dup=false;
    for (int j=0;j<cnt;j++) if (list[j]==m){dup=true;break;}
    if(!dup) list[cnt++]=m;
  }
  edge_cnt[e]=cnt;
  for (int j=0;j<cnt;j++){
    edge_nodes[e*(DEG+1)+j]=list[j];
    atomicAdd(&node_deg[list[j]],1);
  }
}

// ---------------- sim -> mean_sim -> minmax norm -> Wd (one block per b) ------
__global__ void k_sim(const float* __restrict__ feat, const float* __restrict__ W,
                      const int* __restrict__ members, const int* __restrict__ centers,
                      const int* __restrict__ offsets, float* __restrict__ Wd){
  int b = blockIdx.x;
  __shared__ float ms[EE];
  __shared__ float rmn[256], rmx[256];
  const float* fb = feat + (size_t)b*NN*16;
  for (int e=threadIdx.x; e<EE; e+=256){
    int st=offsets[e], en=offsets[e+1];
    int c = centers[e];
    float cf[16]; float nc=0.f;
    #pragma unroll
    for(int d=0;d<16;d++){ cf[d]=fb[c*16+d]; nc+=cf[d]*cf[d]; }
    nc = sqrtf(nc);
    float acc=0.f;
    for(int k=st;k<en;k++){
      int m=members[k];
      float dot=0.f, nm=0.f;
      #pragma unroll
      for(int d=0;d<16;d++){ float vv=fb[m*16+d]; dot+=vv*cf[d]; nm+=vv*vv; }
      float sim = dot/(sqrtf(nm)*nc + EPSF);
      sim = fminf(fmaxf(sim,0.f),1.f);
      acc += sim;
    }
    float count = (float)(en-st);
    ms[e] = acc / fmaxf(count,1.f);
  }
  __syncthreads();
  float mn = 1e30f, mx = -1e30f;
  for(int e=threadIdx.x;e<EE;e+=256){ mn=fminf(mn,ms[e]); mx=fmaxf(mx,ms[e]); }
  rmn[threadIdx.x]=mn; rmx[threadIdx.x]=mx;
  __syncthreads();
  for(int s=128;s>0;s>>=1){
    if(threadIdx.x<s){
      rmn[threadIdx.x]=fminf(rmn[threadIdx.x],rmn[threadIdx.x+s]);
      rmx[threadIdx.x]=fmaxf(rmx[threadIdx.x],rmx[threadIdx.x+s]);
    }
    __syncthreads();
  }
  float smn=rmn[0], smx=rmx[0];
  for(int e=threadIdx.x;e<EE;e+=256){
    float msn = (ms[e]-smn)/(smx-smn+EPSF);
    Wd[b*EE+e] = W[e]*(1.f + LAMF*msn);
  }
}

// ---------------- prefix sum of node_deg -> node_off ----------------
__global__ void k_scan(const int* __restrict__ node_deg, int* __restrict__ node_off){
  __shared__ int buf[1024];
  int i=threadIdx.x;
  buf[i] = (i<NN)? node_deg[i]:0;
  __syncthreads();
  for(int d=1; d<1024; d<<=1){
    int v = (i>=d)? buf[i-d]:0;
    __syncthreads();
    buf[i]+=v;
    __syncthreads();
  }
  if(i<NN) node_off[i+1]=buf[i];
  if(i==0) node_off[0]=0;
}

// ---------------- fill node->edge CSR ----------------
__global__ void k_fill(const int* __restrict__ edge_nodes, const int* __restrict__ edge_cnt,
                       const int* __restrict__ node_off, int* __restrict__ cursor,
                       int* __restrict__ node_edges){
  int e = blockIdx.x*blockDim.x + threadIdx.x;
  if (e>=EE) return;
  int cnt=edge_cnt[e];
  for(int j=0;j<cnt;j++){
    int n=edge_nodes[e*(DEG+1)+j];
    int pos=atomicAdd(&cursor[n],1);
    node_edges[node_off[n]+pos]=e;
  }
}

// ---------------- dv -> dvi ----------------
__global__ void k_dv(const float* __restrict__ Wd, const int* __restrict__ node_off,
                     const int* __restrict__ node_edges, float* __restrict__ dvi){
  int idx = blockIdx.x*blockDim.x + threadIdx.x;
  if (idx>=BB*NN) return;
  int b = idx/NN, n = idx%NN;
  int st=node_off[n], en=node_off[n+1];
  float dv=0.f;
  for(int k=st;k<en;k++) dv += Wd[b*EE + node_edges[k]];
  dvi[idx] = rsqrtf(fmaxf(dv, EPSF));
}

// ---------------- z = dvi * (x @ in_proj_w + b) ----------------
// block 256 = 8 rows x 32 f; rows enumerate (b,t,n) n-fastest
__global__ void k_z(const float* __restrict__ x, const float* __restrict__ ipw,
                    const float* __restrict__ ipb, const float* __restrict__ dvi,
                    float* __restrict__ z){
  __shared__ float ws_[FIN*32];
  __shared__ float bs_[32];
  int tid = threadIdx.x;
  for(int i=tid;i<FIN*32;i+=256) ws_[i]=ipw[i];
  if(tid<32) bs_[tid]=ipb[tid];
  __syncthreads();
  int r = tid>>5, f = tid&31;
  size_t rid = (size_t)blockIdx.x*8 + r;       // < 192000
  int n = (int)(rid % NN);
  int bt = (int)(rid / NN);
  int b = bt / TT;
  const float4* x4 = (const float4*)(x + rid*FIN);
  float acc = bs_[f];
  #pragma unroll
  for(int k=0;k<4;k++){
    float4 xv = x4[k];
    acc = fmaf(xv.x, ws_[(4*k+0)*32+f], acc);
    acc = fmaf(xv.y, ws_[(4*k+1)*32+f], acc);
    acc = fmaf(xv.z, ws_[(4*k+2)*32+f], acc);
    acc = fmaf(xv.w, ws_[(4*k+3)*32+f], acc);
  }
  z[rid*32+f] = dvi[b*NN+n]*acc;
}

// ---------------- v[b,t,e,f] = (Wd/De) * sum_{m in e} z[b,t,m,f] ----------------
__global__ void k_u(const float* __restrict__ z, const float* __restrict__ Wd,
                    const int* __restrict__ edge_nodes, const int* __restrict__ edge_cnt,
                    float* __restrict__ v){
  int tid = threadIdx.x;
  int r = tid>>5, f = tid&31;
  size_t rid = (size_t)blockIdx.x*8 + r;       // over (b,t,e), e fastest
  int e = (int)(rid % EE);
  int bt = (int)(rid / EE);
  int b = bt / TT;
  int cnt = edge_cnt[e];
  const float* zs = z + (size_t)bt*NN*32;
  const int* en = edge_nodes + e*(DEG+1);
  float acc=0.f;
  for(int j=0;j<cnt;j++) acc += zs[en[j]*32+f];
  float wde = Wd[b*EE+e] / (float)cnt;
  v[rid*32+f] = acc*wde;
}

// ---------------- h2=dvi*sum v; hc=silu(h2@conv_w+cb); zx=hc@wx+lstm_b ----------
// block 256 = 8 rows over (b,t,n) n-fastest (1000%8==0 so all rows share (b,t))
__global__ void k_h2conv_zx(const float* __restrict__ v, const float* __restrict__ dvi,
                            const int* __restrict__ node_off, const int* __restrict__ node_edges,
                            const float* __restrict__ cw, const float* __restrict__ cb,
                            const float* __restrict__ wx, const float* __restrict__ lb,
                            float* __restrict__ zx){
  __shared__ float cws[HCN*DM];     // 32x32 (i-major: cw[i][j])
  __shared__ float cbs[HCN];
  __shared__ float wxs[HCN*128];    // 32x128
  __shared__ float lbs[128];
  __shared__ float srow[8][32];
  __shared__ float hrow[8][36];     // padded for bank-conflict-free f4 reads
  int tid = threadIdx.x;
  for(int i=tid;i<HCN*DM;i+=256) cws[i]=cw[i];
  for(int i=tid;i<HCN*128;i+=256) wxs[i]=wx[i];
  if(tid<HCN) cbs[tid]=cb[tid];
  if(tid<128) lbs[tid]=lb[tid];
  int r = tid>>5, f = tid&31;
  size_t rid = (size_t)blockIdx.x*8 + r;      // over (b,t,n)
  int n = (int)(rid % NN);
  int bt = (int)(rid / NN);
  int b = bt / TT;
  int t = bt % TT;
  __syncthreads();
  // phase 1: gather over edges containing n
  {
    int st=node_off[n], en=node_off[n+1];
    const float* vs = v + (size_t)bt*EE*32;
    float acc=0.f;
    for(int k=st;k<en;k++) acc += vs[node_edges[k]*32+f];
    srow[r][f] = acc * dvi[b*NN+n];
  }
  __syncthreads();
  // phase 2: conv 32->32 + silu
  {
    float a = cbs[f];
    #pragma unroll
    for(int i=0;i<DM;i++) a = fmaf(srow[r][i], cws[i*32+f], a);
    hrow[r][f] = siluf_(a);
  }
  __syncthreads();
  // phase 3: zx = hc @ wx + lb ; thread (q=tid/8, rr=tid%8) -> cols 4q..4q+3 of row rr
  {
    int q = tid>>3, rr = tid&7;
    size_t rrid = (size_t)blockIdx.x*8 + rr;
    int nn_ = (int)(rrid % NN);
    float hreg[32];
    #pragma unroll
    for(int k=0;k<8;k++){
      float4 h4 = *(const float4*)&hrow[rr][4*k];
      hreg[4*k+0]=h4.x; hreg[4*k+1]=h4.y; hreg[4*k+2]=h4.z; hreg[4*k+3]=h4.w;
    }
    float4 o = *(const float4*)&lbs[4*q];
    #pragma unroll
    for(int i=0;i<HCN;i++){
      float4 wv = *(const float4*)&wxs[i*128 + 4*q];
      o.x = fmaf(hreg[i], wv.x, o.x);
      o.y = fmaf(hreg[i], wv.y, o.y);
      o.z = fmaf(hreg[i], wv.z, o.z);
      o.w = fmaf(hreg[i], wv.w, o.w);
    }
    size_t zbase = ((size_t)(b*NN+nn_)*TT + t)*128;
    *(float4*)&zx[zbase + 4*q] = o;
  }
}

// ---------------- LSTM over T (serial) + fused head ----------------
// block 64 = 1 wave = 2 rows; 32 lanes per row, lane c owns channel c.
__global__ __launch_bounds__(64) void k_lstm(const float* __restrict__ zx,
    const float* __restrict__ wh,
    const float* __restrict__ w1, const float* __restrict__ b1,
    const float* __restrict__ w2, const float* __restrict__ b2,
    float* __restrict__ out){
  int lane = threadIdx.x; int sub = lane>>5; int c = lane&31;
  int row = blockIdx.x*2 + sub;     // < 8000
  int b = row/NN; int n = row%NN;
  int base = sub<<5;
  float wr0[32], wr1[32], wr2[32], wr3[32];
  #pragma unroll
  for(int i=0;i<32;i++){
    wr0[i]=wh[i*128 + c];
    wr1[i]=wh[i*128 + 32 + c];
    wr2[i]=wh[i*128 + 64 + c];
    wr3[i]=wh[i*128 + 96 + c];
  }
  const float* zr = zx + (size_t)row*TT*128;
  float h=0.f, cs=0.f;
  float p0=zr[c], p1=zr[32+c], p2=zr[64+c], p3=zr[96+c];
  for(int t=0;t<TT;t++){
    float z0=p0, z1=p1, z2=p2, z3=p3;
    if(t+1<TT){
      const float* q=zr+(size_t)(t+1)*128;
      p0=q[c]; p1=q[32+c]; p2=q[64+c]; p3=q[96+c];
    }
    #pragma unroll
    for(int i=0;i<32;i++){
      float hv = __shfl(h, base+i, 64);
      z0 = fmaf(hv, wr0[i], z0);
      z1 = fmaf(hv, wr1[i], z1);
      z2 = fmaf(hv, wr2[i], z2);
      z3 = fmaf(hv, wr3[i], z3);
    }
    float ig = sigmoidf_(z0);
    float fg = sigmoidf_(z1);
    float gg = tanhf(z2);
    float og = sigmoidf_(z3);
    cs = fg*cs + ig*gg;
    h = og*tanhf(cs);
  }
  // head: t1 = silu(h@w1+b1); y = t1@w2+b2; out[b][p][n] = y[p]
  float t1 = b1[c];
  #pragma unroll
  for(int i=0;i<32;i++){ float hv=__shfl(h, base+i, 64); t1 = fmaf(hv, w1[i*32+c], t1); }
  t1 = siluf_(t1);
  float y = (c<PREDN)? b2[c] : 0.f;
  #pragma unroll
  for(int i=0;i<32;i++){
    float tv=__shfl(t1, base+i, 64);
    if(c<PREDN) y = fmaf(tv, w2[i*PREDN+c], y);
  }
  if(c<PREDN) out[((size_t)b*PREDN + c)*NN + n] = y;
}

extern "C" void kernel_launch(void* const* d_in, const int* in_sizes, int n_in,
                              void* d_out, int out_size, void* d_ws, size_t ws_size,
                              hipStream_t stream) {
  const float* x       = (const float*)d_in[0];
  const float* xraw    = (const float*)d_in[1];
  // d_in[2] = H (dense) unused: reconstructed from members/centers
  const float* W       = (const float*)d_in[3];
  const int*   members = (const int*)d_in[4];
  const int*   centers = (const int*)d_in[5];
  const int*   offsets = (const int*)d_in[6];
  const float* ipw     = (const float*)d_in[7];
  const float* ipb     = (const float*)d_in[8];
  const float* cw      = (const float*)d_in[9];
  const float* cb      = (const float*)d_in[10];
  const float* wx      = (const float*)d_in[11];
  const float* wh      = (const float*)d_in[12];
  const float* lb      = (const float*)d_in[13];
  const float* w1      = (const float*)d_in[14];
  const float* b1      = (const float*)d_in[15];
  const float* w2      = (const float*)d_in[16];
  const float* b2      = (const float*)d_in[17];
  float* out = (float*)d_out;

  float* zx   = (float*)d_ws;                 // 24,576,000
  float* z    = zx + 24576000;                // 6,144,000
  float* v    = z  + 6144000;                 // 6,144,000
  float* feat = v  + 6144000;                 // 128,000
  float* Wd   = feat + 128000;                // 8,000
  float* dvi  = Wd + 8000;                    // 8,000
  int* edge_nodes = (int*)(dvi + 8000);       // 21,000
  int* edge_cnt   = edge_nodes + 21000;       // 1,000
  int* node_off   = edge_cnt + 1000;          // 1,002
  int* node_deg   = node_off + 1002;          // 1,000
  int* cursor     = node_deg + 1000;          // 1,000
  int* node_edges = cursor + 1000;            // 21,000

  hipMemsetAsync(node_deg, 0, 2000*sizeof(int), stream);  // node_deg + cursor

  k_feat<<<(BB*NN+255)/256, 256, 0, stream>>>(xraw, feat);
  k_edges<<<(EE+255)/256, 256, 0, stream>>>(members, centers, offsets,
                                            edge_nodes, edge_cnt, node_deg);
  k_sim<<<BB, 256, 0, stream>>>(feat, W, members, centers, offsets, Wd);
  k_scan<<<1, 1024, 0, stream>>>(node_deg, node_off);
  k_fill<<<(EE+255)/256, 256, 0, stream>>>(edge_nodes, edge_cnt, node_off, cursor, node_edges);
  k_dv<<<(BB*NN+255)/256, 256, 0, stream>>>(Wd, node_off, node_edges, dvi);
  k_z<<<(BB*TT*NN)/8, 256, 0, stream>>>(x, ipw, ipb, dvi, z);
  k_u<<<(BB*TT*EE)/8, 256, 0, stream>>>(z, Wd, edge_nodes, edge_cnt, v);
  k_h2conv_zx<<<(BB*TT*NN)/8, 256, 0, stream>>>(v, dvi, node_off, node_edges,
                                                cw, cb, wx, lb, zx);
  k_lstm<<<(BB*NN)/2, 64, 0, stream>>>(zx, wh, w1, b1, w2, b2, out);
}

// Round 2
// 559.257 us; speedup vs baseline: 1.2925x; 1.2925x over previous
//
#include <hip/hip_runtime.h>
#include <hip/hip_bf16.h>
#include <math.h>

// Problem constants (SingleHyperTKAN)
#define BB 8
#define TT 24
#define NN 1000
#define EE 1000
#define DEG 20
#define FIN 16
#define CRAW 8
#define DM 32
#define HCN 32
#define TKN 32
#define PREDN 12
#define LAMF 0.3f
#define EPSF 1e-8f

#define NGRP 24000   // BB*TT*NN/8

__device__ __forceinline__ float sigmoidf_(float x){ return 1.f/(1.f+__expf(-x)); }
__device__ __forceinline__ float siluf_(float x){ return x/(1.f+__expf(-x)); }

// ---------------- feat: mean/std over T (coalesced (n,c) layout) ----------------
// block 256 = 32 n x 8 c ; grid 250
__global__ void k_feat(const float* __restrict__ xraw, float* __restrict__ feat){
  int tid = threadIdx.x;
  int c = tid & 7, nloc = tid >> 3;
  int row = blockIdx.x*32 + nloc;          // (b*N+n) < 8000
  if (row >= BB*NN) return;
  int b = row/NN, n = row%NN;
  float s=0.f, s2=0.f;
  for (int t=0;t<TT;t++){
    float vv = xraw[(((size_t)(b*TT+t)*NN + n)*CRAW) + c];
    s += vv; s2 += vv*vv;
  }
  float m = s*(1.f/TT);
  float var = fmaxf(s2*(1.f/TT) - m*m, 0.f);
  feat[(size_t)row*16 + c]     = m;
  feat[(size_t)row*16 + 8 + c] = sqrtf(var);
}

// ---------------- edge dedup + De + node degree counts ----------------
__global__ void k_edges(const int* __restrict__ members, const int* __restrict__ centers,
                        const int* __restrict__ offsets,
                        int* __restrict__ edge_nodes, int* __restrict__ edge_cnt,
                        int* __restrict__ node_deg){
  int e = blockIdx.x*blockDim.x + threadIdx.x;
  if (e>=EE) return;
  int st = offsets[e], en = offsets[e+1];
  int list[DEG+1]; int cnt=0;
  list[cnt++] = centers[e];
  for (int k=st;k<en;k++){
    int m = members[k];
    bool dup=false;
    for (int j=0;j<cnt;j++) if (list[j]==m){dup=true;break;}
    if(!dup) list[cnt++]=m;
  }
  edge_cnt[e]=cnt;
  for (int j=0;j<cnt;j++){
    edge_nodes[e*(DEG+1)+j]=list[j];
    atomicAdd(&node_deg[list[j]],1);
  }
}

// ---------------- sim -> mean_sim -> minmax norm -> Wd (block 1024 per b) ------
__global__ __launch_bounds__(1024) void k_sim(const float* __restrict__ feat,
                      const float* __restrict__ W,
                      const int* __restrict__ members, const int* __restrict__ centers,
                      const int* __restrict__ offsets, float* __restrict__ Wd){
  int b = blockIdx.x;
  int tid = threadIdx.x;
  int e = tid;
  __shared__ float red1[1024], red2[1024];
  const float* fb = feat + (size_t)b*NN*16;
  float msv = 0.f;
  if (e < EE){
    int st=offsets[e], en=offsets[e+1];
    int cidx = centers[e];
    float cf[16]; float nc=0.f;
    #pragma unroll
    for(int d=0;d<16;d++){ cf[d]=fb[cidx*16+d]; nc+=cf[d]*cf[d]; }
    nc = sqrtf(nc);
    float accs=0.f;
    for(int k=st;k<en;k++){
      int m=members[k];
      float dot=0.f, nm=0.f;
      #pragma unroll
      for(int d=0;d<16;d++){ float vv=fb[m*16+d]; dot+=vv*cf[d]; nm+=vv*vv; }
      float sim = dot/(sqrtf(nm)*nc + EPSF);
      sim = fminf(fmaxf(sim,0.f),1.f);
      accs += sim;
    }
    msv = accs / fmaxf((float)(en-st),1.f);
  }
  red1[tid] = (e<EE)? msv : 1e30f;
  red2[tid] = (e<EE)? msv : -1e30f;
  __syncthreads();
  for(int s=512;s>0;s>>=1){
    if(tid<s){
      red1[tid]=fminf(red1[tid],red1[tid+s]);
      red2[tid]=fmaxf(red2[tid],red2[tid+s]);
    }
    __syncthreads();
  }
  if (e<EE){
    float msn = (msv - red1[0])/(red2[0]-red1[0]+EPSF);
    Wd[b*EE+e] = W[e]*(1.f + LAMF*msn);
  }
}

// ---------------- prefix sum of node_deg -> node_off ----------------
__global__ void k_scan(const int* __restrict__ node_deg, int* __restrict__ node_off){
  __shared__ int buf[1024];
  int i=threadIdx.x;
  buf[i] = (i<NN)? node_deg[i]:0;
  __syncthreads();
  for(int d=1; d<1024; d<<=1){
    int v = (i>=d)? buf[i-d]:0;
    __syncthreads();
    buf[i]+=v;
    __syncthreads();
  }
  if(i<NN) node_off[i+1]=buf[i];
  if(i==0) node_off[0]=0;
}

// ---------------- fill node->edge CSR ----------------
__global__ void k_fill(const int* __restrict__ edge_nodes, const int* __restrict__ edge_cnt,
                       const int* __restrict__ node_off, int* __restrict__ cursor,
                       int* __restrict__ node_edges){
  int e = blockIdx.x*blockDim.x + threadIdx.x;
  if (e>=EE) return;
  int cnt=edge_cnt[e];
  for(int j=0;j<cnt;j++){
    int n=edge_nodes[e*(DEG+1)+j];
    int pos=atomicAdd(&cursor[n],1);
    node_edges[node_off[n]+pos]=e;
  }
}

// ---------------- dv -> dvi ----------------
__global__ void k_dv(const float* __restrict__ Wd, const int* __restrict__ node_off,
                     const int* __restrict__ node_edges, float* __restrict__ dvi){
  int idx = blockIdx.x*blockDim.x + threadIdx.x;
  if (idx>=BB*NN) return;
  int b = idx/NN, n = idx%NN;
  int st=node_off[n], en=node_off[n+1];
  float dv=0.f;
  for(int k=st;k<en;k++) dv += Wd[b*EE + node_edges[k]];
  dvi[idx] = rsqrtf(fmaxf(dv, EPSF));
}

// ---------------- z = dvi * (x @ in_proj_w + b), persistent ----------------
// block 256 = 8 rows x 32 f; grid 1600, strided groups
__global__ void k_z(const float* __restrict__ x, const float* __restrict__ ipw,
                    const float* __restrict__ ipb, const float* __restrict__ dvi,
                    float* __restrict__ z){
  __shared__ float ws_[FIN*32];
  __shared__ float bs_[32];
  int tid = threadIdx.x;
  for(int i=tid;i<FIN*32;i+=256) ws_[i]=ipw[i];
  if(tid<32) bs_[tid]=ipb[tid];
  __syncthreads();
  int r = tid>>5, f = tid&31;
  for (int g = blockIdx.x; g < NGRP; g += gridDim.x){
    size_t rid = (size_t)g*8 + r;              // < 192000
    int n = (int)(rid % NN);
    int bt = (int)(rid / NN);
    int b = bt / TT;
    const float4* x4 = (const float4*)(x + rid*FIN);
    float acc = bs_[f];
    #pragma unroll
    for(int k=0;k<4;k++){
      float4 xv = x4[k];
      acc = fmaf(xv.x, ws_[(4*k+0)*32+f], acc);
      acc = fmaf(xv.y, ws_[(4*k+1)*32+f], acc);
      acc = fmaf(xv.z, ws_[(4*k+2)*32+f], acc);
      acc = fmaf(xv.w, ws_[(4*k+3)*32+f], acc);
    }
    z[rid*32+f] = dvi[b*NN+n]*acc;
  }
}

// ---------------- v[b,t,e,f] = (Wd/De) * sum_{m in e} z[b,t,m,f] ----------------
// grid 1000 = b(8) x echunk(125); block 256 = 8 edges x 32 f; loop t
__global__ void k_u(const float* __restrict__ z, const float* __restrict__ Wd,
                    const int* __restrict__ edge_nodes, const int* __restrict__ edge_cnt,
                    float* __restrict__ v){
  __shared__ int idx_lds[8][DEG+1];
  int tid = threadIdx.x;
  int b  = blockIdx.x / 125;
  int ec = blockIdx.x % 125;
  int e0 = ec*8;
  for (int i=tid; i<8*(DEG+1); i+=256){
    int el = i/(DEG+1), j = i - el*(DEG+1);
    idx_lds[el][j] = edge_nodes[(e0+el)*(DEG+1) + j];
  }
  int el = tid>>5, f = tid&31;
  int e = e0 + el;
  int cnt = edge_cnt[e];
  float wde = Wd[b*EE+e] / (float)cnt;
  __syncthreads();
  for (int t=0;t<TT;t++){
    int bt = b*TT+t;
    const float* zs = z + (size_t)bt*NN*32;
    float acc=0.f;
    for (int j=0;j<cnt;j++) acc += zs[(size_t)idx_lds[el][j]*32 + f];
    v[((size_t)bt*EE+e)*32+f] = acc*wde;
  }
}

// ---------------- h2=dvi*sum v; hc=silu(h2@conv_w+cb); zx=hc@wx+lstm_b ----------
// persistent: grid 1500, strided groups (concurrent groups share bt-slices)
__global__ void k_h2conv_zx(const float* __restrict__ v, const float* __restrict__ dvi,
                            const int* __restrict__ node_off, const int* __restrict__ node_edges,
                            const float* __restrict__ cw, const float* __restrict__ cb,
                            const float* __restrict__ wx, const float* __restrict__ lb,
                            float* __restrict__ zx){
  __shared__ float cws[HCN*DM];     // 32x32 (i-major)
  __shared__ float cbs[HCN];
  __shared__ float wxs[HCN*128];    // 32x128
  __shared__ float lbs[128];
  __shared__ float srow[8][32];
  __shared__ float hrow[8][36];     // padded
  int tid = threadIdx.x;
  for(int i=tid;i<HCN*DM;i+=256) cws[i]=cw[i];
  for(int i=tid;i<HCN*128;i+=256) wxs[i]=wx[i];
  if(tid<HCN) cbs[tid]=cb[tid];
  if(tid<128) lbs[tid]=lb[tid];
  int r = tid>>5, f = tid&31;
  int wbase = ((tid>>5)&1)<<5;      // shfl base within wave
  int q = tid>>3, rr = tid&7;       // phase-3 mapping
  for (int g = blockIdx.x; g < NGRP; g += gridDim.x){
    size_t rid = (size_t)g*8 + r;
    int n = (int)(rid % NN);
    int bt = (int)(rid / NN);
    int b = bt / TT;
    __syncthreads();   // protect srow/hrow reuse; first iter covers weight loads
    // phase 1: gather over edges containing n (lane-spread indices + shfl)
    {
      int st=node_off[n], en=node_off[n+1];
      const float* vs = v + (size_t)bt*EE*32;
      float acc=0.f;
      for (int c0=st; c0<en; c0+=32){
        int rem = en - c0;
        int idx = 0;
        if (f < rem) idx = node_edges[c0 + f];
        int m = rem < 32 ? rem : 32;
        for (int j=0;j<m;j++){
          int ee = __shfl(idx, wbase + j, 64);
          acc += vs[(size_t)ee*32 + f];
        }
      }
      srow[r][f] = acc * dvi[b*NN+n];
    }
    __syncthreads();
    // phase 2: conv 32->32 + silu
    {
      float a = cbs[f];
      #pragma unroll
      for(int i=0;i<DM;i++) a = fmaf(srow[r][i], cws[i*32+f], a);
      hrow[r][f] = siluf_(a);
    }
    __syncthreads();
    // phase 3: zx = hc @ wx + lb ; thread (q,rr) -> cols 4q..4q+3 of row rr
    {
      size_t rrid = (size_t)g*8 + rr;
      int nn_ = (int)(rrid % NN);
      int bt_ = (int)(rrid / NN);
      int b_ = bt_ / TT;
      int t_ = bt_ % TT;
      float hreg[32];
      #pragma unroll
      for(int k=0;k<8;k++){
        float4 h4 = *(const float4*)&hrow[rr][4*k];
        hreg[4*k+0]=h4.x; hreg[4*k+1]=h4.y; hreg[4*k+2]=h4.z; hreg[4*k+3]=h4.w;
      }
      float4 o = *(const float4*)&lbs[4*q];
      #pragma unroll
      for(int i=0;i<HCN;i++){
        float4 wv = *(const float4*)&wxs[i*128 + 4*q];
        o.x = fmaf(hreg[i], wv.x, o.x);
        o.y = fmaf(hreg[i], wv.y, o.y);
        o.z = fmaf(hreg[i], wv.z, o.z);
        o.w = fmaf(hreg[i], wv.w, o.w);
      }
      size_t zbase = ((size_t)(b_*NN+nn_)*TT + t_)*128;
      *(float4*)&zx[zbase + 4*q] = o;
    }
  }
}

// ---------------- LSTM over T (serial) + fused head ----------------
__global__ __launch_bounds__(64) void k_lstm(const float* __restrict__ zx,
    const float* __restrict__ wh,
    const float* __restrict__ w1, const float* __restrict__ b1,
    const float* __restrict__ w2, const float* __restrict__ b2,
    float* __restrict__ out){
  int lane = threadIdx.x; int sub = lane>>5; int c = lane&31;
  int row = blockIdx.x*2 + sub;     // < 8000
  int b = row/NN; int n = row%NN;
  int base = sub<<5;
  float wr0[32], wr1[32], wr2[32], wr3[32];
  #pragma unroll
  for(int i=0;i<32;i++){
    wr0[i]=wh[i*128 + c];
    wr1[i]=wh[i*128 + 32 + c];
    wr2[i]=wh[i*128 + 64 + c];
    wr3[i]=wh[i*128 + 96 + c];
  }
  const float* zr = zx + (size_t)row*TT*128;
  float h=0.f, cs=0.f;
  float p0=zr[c], p1=zr[32+c], p2=zr[64+c], p3=zr[96+c];
  for(int t=0;t<TT;t++){
    float z0=p0, z1=p1, z2=p2, z3=p3;
    if(t+1<TT){
      const float* qq=zr+(size_t)(t+1)*128;
      p0=qq[c]; p1=qq[32+c]; p2=qq[64+c]; p3=qq[96+c];
    }
    #pragma unroll
    for(int i=0;i<32;i++){
      float hv = __shfl(h, base+i, 64);
      z0 = fmaf(hv, wr0[i], z0);
      z1 = fmaf(hv, wr1[i], z1);
      z2 = fmaf(hv, wr2[i], z2);
      z3 = fmaf(hv, wr3[i], z3);
    }
    float ig = sigmoidf_(z0);
    float fg = sigmoidf_(z1);
    float gg = tanhf(z2);
    float og = sigmoidf_(z3);
    cs = fg*cs + ig*gg;
    h = og*tanhf(cs);
  }
  float t1 = b1[c];
  #pragma unroll
  for(int i=0;i<32;i++){ float hv=__shfl(h, base+i, 64); t1 = fmaf(hv, w1[i*32+c], t1); }
  t1 = siluf_(t1);
  float y = (c<PREDN)? b2[c] : 0.f;
  #pragma unroll
  for(int i=0;i<32;i++){
    float tv=__shfl(t1, base+i, 64);
    if(c<PREDN) y = fmaf(tv, w2[i*PREDN+c], y);
  }
  if(c<PREDN) out[((size_t)b*PREDN + c)*NN + n] = y;
}

extern "C" void kernel_launch(void* const* d_in, const int* in_sizes, int n_in,
                              void* d_out, int out_size, void* d_ws, size_t ws_size,
                              hipStream_t stream) {
  const float* x       = (const float*)d_in[0];
  const float* xraw    = (const float*)d_in[1];
  const float* W       = (const float*)d_in[3];
  const int*   members = (const int*)d_in[4];
  const int*   centers = (const int*)d_in[5];
  const int*   offsets = (const int*)d_in[6];
  const float* ipw     = (const float*)d_in[7];
  const float* ipb     = (const float*)d_in[8];
  const float* cw      = (const float*)d_in[9];
  const float* cb      = (const float*)d_in[10];
  const float* wx      = (const float*)d_in[11];
  const float* wh      = (const float*)d_in[12];
  const float* lb      = (const float*)d_in[13];
  const float* w1      = (const float*)d_in[14];
  const float* b1      = (const float*)d_in[15];
  const float* w2      = (const float*)d_in[16];
  const float* b2      = (const float*)d_in[17];
  float* out = (float*)d_out;

  float* zx   = (float*)d_ws;                 // 24,576,000
  float* z    = zx + 24576000;                // 6,144,000
  float* v    = z  + 6144000;                 // 6,144,000
  float* feat = v  + 6144000;                 // 128,000
  float* Wd   = feat + 128000;                // 8,000
  float* dvi  = Wd + 8000;                    // 8,000
  int* edge_nodes = (int*)(dvi + 8000);       // 21,000
  int* edge_cnt   = edge_nodes + 21000;       // 1,000
  int* node_off   = edge_cnt + 1000;          // 1,002
  int* node_deg   = node_off + 1002;          // 1,000
  int* cursor     = node_deg + 1000;          // 1,000
  int* node_edges = cursor + 1000;            // 21,000

  hipMemsetAsync(node_deg, 0, 2000*sizeof(int), stream);  // node_deg + cursor

  k_feat<<<250, 256, 0, stream>>>(xraw, feat);
  k_edges<<<(EE+255)/256, 256, 0, stream>>>(members, centers, offsets,
                                            edge_nodes, edge_cnt, node_deg);
  k_sim<<<BB, 1024, 0, stream>>>(feat, W, members, centers, offsets, Wd);
  k_scan<<<1, 1024, 0, stream>>>(node_deg, node_off);
  k_fill<<<(EE+255)/256, 256, 0, stream>>>(edge_nodes, edge_cnt, node_off, cursor, node_edges);
  k_dv<<<(BB*NN+255)/256, 256, 0, stream>>>(Wd, node_off, node_edges, dvi);
  k_z<<<1600, 256, 0, stream>>>(x, ipw, ipb, dvi, z);
  k_u<<<1000, 256, 0, stream>>>(z, Wd, edge_nodes, edge_cnt, v);
  k_h2conv_zx<<<1500, 256, 0, stream>>>(v, dvi, node_off, node_edges,
                                        cw, cb, wx, lb, zx);
  k_lstm<<<(BB*NN)/2, 64, 0, stream>>>(zx, wh, w1, b1, w2, b2, out);
}

// Round 4
// 547.987 us; speedup vs baseline: 1.3191x; 1.0206x over previous
//
#include <hip/hip_runtime.h>
#include <hip/hip_bf16.h>
#include <math.h>

// Problem constants (SingleHyperTKAN)
#define BB 8
#define TT 24
#define NN 1000
#define EE 1000
#define DEG 20
#define FIN 16
#define CRAW 8
#define DM 32
#define HCN 32
#define TKN 32
#define PREDN 12
#define LAMF 0.3f
#define EPSF 1e-8f

__device__ __forceinline__ float sigmoidf_(float x){ return 1.f/(1.f+__expf(-x)); }
__device__ __forceinline__ float siluf_(float x){ return x/(1.f+__expf(-x)); }
__device__ __forceinline__ float tanhf_(float x){
  float xx = fminf(fmaxf(x,-15.f),15.f);
  float e = __expf(2.f*xx);
  return (e-1.f)/(e+1.f);
}

// ============ k_prep: dedup edges + node degree + scan + CSR fill (1 block) ====
__global__ __launch_bounds__(1024) void k_prep(
    const int* __restrict__ members, const int* __restrict__ centers,
    const int* __restrict__ offsets,
    int* __restrict__ edge_nodes, int* __restrict__ edge_cnt,
    int* __restrict__ node_off, int* __restrict__ node_edges)
{
  __shared__ int deg[NN];
  __shared__ int cur[NN];
  __shared__ int offs[NN+1];
  __shared__ int buf[1024];
  int tid = threadIdx.x;
  for(int i=tid;i<NN;i+=1024){ deg[i]=0; cur[i]=0; }
  __syncthreads();
  int e = tid;
  int cnt = 0;
  if(e<EE){
    int st=offsets[e], en=offsets[e+1];
    int c=centers[e];
    edge_nodes[e*(DEG+1)+0]=c;
    atomicAdd(&deg[c],1);
    cnt=1;
    for(int k=st;k<en;k++){
      int m=members[k];
      bool dup=(m==c);
      for(int k2=st;k2<k && !dup;k2++) if(members[k2]==m) dup=true;
      if(!dup){
        edge_nodes[e*(DEG+1)+cnt]=m;
        atomicAdd(&deg[m],1);
        cnt++;
      }
    }
    edge_cnt[e]=cnt;
  }
  __syncthreads();
  buf[tid] = (tid<NN)? deg[tid] : 0;
  __syncthreads();
  for(int d=1;d<1024;d<<=1){
    int v = (tid>=d)? buf[tid-d] : 0;
    __syncthreads();
    buf[tid]+=v;
    __syncthreads();
  }
  if(tid==0) offs[0]=0;
  if(tid<NN) offs[tid+1]=buf[tid];
  __syncthreads();
  if(tid<=NN) node_off[tid]=offs[tid];
  if(e<EE){
    for(int j=0;j<cnt;j++){
      int n = edge_nodes[e*(DEG+1)+j];   // same-thread RAW: program-order safe
      int pos = atomicAdd(&cur[n],1);
      node_edges[offs[n]+pos] = e;
    }
  }
}

// ============ k_simf: feat (LDS only) + sim + minmax + Wd ; one block per b ====
__global__ __launch_bounds__(1024) void k_simf(
    const float* __restrict__ xraw, const float* __restrict__ W,
    const int* __restrict__ members, const int* __restrict__ centers,
    const int* __restrict__ offsets, float* __restrict__ Wd)
{
  __shared__ float fl[NN*17];      // padded stride 17 (bank spread)
  __shared__ float nrm[NN];
  __shared__ float red1[1024], red2[1024];
  int b = blockIdx.x;
  int tid = threadIdx.x;
  int c = tid&7, nl = tid>>3;      // 128 nodes per pass
  for(int p=0;p<8;p++){
    int n = p*128+nl;
    if(n<NN){
      float s=0.f, s2=0.f;
      for(int t=0;t<TT;t++){
        float vv = xraw[(((size_t)(b*TT+t)*NN + n))*CRAW + c];
        s+=vv; s2+=vv*vv;
      }
      float m = s*(1.f/TT);
      float var = fmaxf(s2*(1.f/TT)-m*m, 0.f);
      fl[n*17+c]   = m;
      fl[n*17+8+c] = sqrtf(var);
    }
  }
  __syncthreads();
  if(tid<NN){
    float s=0.f;
    #pragma unroll
    for(int d=0;d<16;d++){ float v=fl[tid*17+d]; s=fmaf(v,v,s); }
    nrm[tid]=sqrtf(s);
  }
  __syncthreads();
  float msv = 0.f;
  int e = tid;
  if(e<EE){
    int st=offsets[e], en=offsets[e+1];
    int ci=centers[e];
    float cf[16];
    #pragma unroll
    for(int d=0;d<16;d++) cf[d]=fl[ci*17+d];
    float nc=nrm[ci];
    float acc=0.f;
    for(int k=st;k<en;k++){
      int m=members[k];
      float dot=0.f;
      #pragma unroll
      for(int d=0;d<16;d++) dot=fmaf(fl[m*17+d],cf[d],dot);
      float sim = dot/(nrm[m]*nc+EPSF);
      acc += fminf(fmaxf(sim,0.f),1.f);
    }
    msv = acc/fmaxf((float)(en-st),1.f);
  }
  red1[tid]=(e<EE)? msv : 1e30f;
  red2[tid]=(e<EE)? msv : -1e30f;
  __syncthreads();
  for(int s=512;s>0;s>>=1){
    if(tid<s){
      red1[tid]=fminf(red1[tid],red1[tid+s]);
      red2[tid]=fmaxf(red2[tid],red2[tid+s]);
    }
    __syncthreads();
  }
  if(e<EE){
    float msn=(msv-red1[0])/(red2[0]-red1[0]+EPSF);
    Wd[b*EE+e]=W[e]*(1.f+LAMF*msn);
  }
}

// ============ k_dv: dvi = rsqrt(clip(sum_{e∋n} Wd[b,e])) ====
__global__ void k_dv(const float* __restrict__ Wd, const int* __restrict__ node_off,
                     const int* __restrict__ node_edges, float* __restrict__ dvi){
  int idx = blockIdx.x*blockDim.x + threadIdx.x;
  if (idx>=BB*NN) return;
  int b = idx/NN, n = idx%NN;
  int st=node_off[n], en=node_off[n+1];
  float dv=0.f;
  for(int k=st;k<en;k++) dv += Wd[b*EE + node_edges[k]];
  dvi[idx] = rsqrtf(fmaxf(dv, EPSF));
}

// ============ k_slice: per-(b,t) fused z -> v -> h2 -> conv -> zx ====
// grid 192 (=B*T), block 1024 = 32 groups x 32 lanes. LDS ~148 KB.
__global__ __launch_bounds__(1024) void k_slice(
    const float* __restrict__ x,
    const float* __restrict__ ipw, const float* __restrict__ ipb,
    const float* __restrict__ dvi, const float* __restrict__ Wd,
    const int* __restrict__ edge_nodes, const int* __restrict__ edge_cnt,
    const int* __restrict__ node_off, const int* __restrict__ node_edges,
    const float* __restrict__ cw, const float* __restrict__ cb,
    const float* __restrict__ wx, const float* __restrict__ lb,
    float* __restrict__ zx)
{
  __shared__ float zbuf[NN*32];     // 125 KB: z, then overwritten by v
  __shared__ float ipws[FIN*32];    // 2 KB
  __shared__ float cws[DM*HCN];     // 4 KB
  __shared__ float wxs[HCN*128];    // 16 KB
  __shared__ float ipbs[32], cbs[32], lbs[128];

  int tid = threadIdx.x;
  int bt  = blockIdx.x;
  int b = bt / TT, t = bt % TT;
  int f = tid & 31, g = tid >> 5;   // group g handles rows p*32+g
  int wbase = (g & 1) << 5;         // shfl base inside the 64-lane wave

  for(int i=tid;i<FIN*32;i+=1024) ipws[i]=ipw[i];
  for(int i=tid;i<DM*HCN;i+=1024) cws[i]=cw[i];
  for(int i=tid;i<HCN*128;i+=1024) wxs[i]=wx[i];
  if(tid<32) ipbs[tid]=ipb[tid];
  if(tid>=64 && tid<96) cbs[tid-64]=cb[tid-64];
  if(tid>=128 && tid<256) lbs[tid-128]=lb[tid-128];
  __syncthreads();

  const float* xb  = x + (size_t)bt*NN*FIN;
  const float* dvb = dvi + b*NN;

  // ---- Phase A: z[r,f] = dvi * (x @ ipw + ipb) into zbuf ----
  for(int p=0;p<32;p++){
    int r = p*32+g;
    if(r<NN){
      const float4* x4 = (const float4*)(xb + r*FIN);
      float acc = ipbs[f];
      #pragma unroll
      for(int k=0;k<4;k++){
        float4 xv = x4[k];
        acc = fmaf(xv.x, ipws[(4*k+0)*32+f], acc);
        acc = fmaf(xv.y, ipws[(4*k+1)*32+f], acc);
        acc = fmaf(xv.z, ipws[(4*k+2)*32+f], acc);
        acc = fmaf(xv.w, ipws[(4*k+3)*32+f], acc);
      }
      zbuf[r*32+f] = dvb[r]*acc;
    }
  }
  __syncthreads();

  // ---- Phase B: v[e,f] = (Wd/De) * sum_{m in e} z[m,f] into regs ----
  float vreg[32];
  #pragma unroll
  for(int p=0;p<32;p++){
    int e = p*32+g;
    float val = 0.f;
    if(e<EE){
      int cnt  = edge_cnt[e];
      float wde = Wd[b*EE+e]/(float)cnt;
      int idx = (f<cnt)? edge_nodes[e*(DEG+1)+f] : 0;
      float acc=0.f;
      for(int j=0;j<cnt;j++){
        int m = __shfl(idx, wbase+j, 64);
        acc += zbuf[m*32+f];
      }
      val = acc*wde;
    }
    vreg[p]=val;
  }
  __syncthreads();
  // ---- Phase C: overwrite zbuf with v ----
  #pragma unroll
  for(int p=0;p<32;p++){
    int e = p*32+g;
    if(e<EE) zbuf[e*32+f]=vreg[p];
  }
  __syncthreads();

  // ---- Phase D: h2 gather -> conv+silu -> zx projection ----
  for(int p=0;p<32;p++){
    int n = p*32+g;
    if(n<NN){
      int st=node_off[n], en=node_off[n+1];
      float acc=0.f;
      for(int c0=st;c0<en;c0+=32){
        int rem = en-c0;
        int idx = (f<rem)? node_edges[c0+f] : 0;
        int m_ = rem<32 ? rem : 32;
        for(int j=0;j<m_;j++){
          int ee = __shfl(idx, wbase+j, 64);
          acc += zbuf[ee*32+f];
        }
      }
      float h2v = acc*dvb[n];
      // conv 32->32 + silu
      float a = cbs[f];
      #pragma unroll
      for(int i=0;i<DM;i++){
        float hv = __shfl(h2v, wbase+i, 64);
        a = fmaf(hv, cws[i*32+f], a);
      }
      float hc = siluf_(a);
      // zx = hc @ wx + lb ; lane f owns cols 4f..4f+3
      float4 o = *(const float4*)&lbs[4*f];
      #pragma unroll
      for(int i=0;i<HCN;i++){
        float hv = __shfl(hc, wbase+i, 64);
        float4 wv = *(const float4*)&wxs[i*128+4*f];
        o.x = fmaf(hv, wv.x, o.x);
        o.y = fmaf(hv, wv.y, o.y);
        o.z = fmaf(hv, wv.z, o.z);
        o.w = fmaf(hv, wv.w, o.w);
      }
      *(float4*)&zx[((size_t)(b*NN+n)*TT + t)*128 + 4*f] = o;
    }
  }
}

// ============ k_lstm: serial T recurrence + fused head ====
// block 256 = 4 waves = 8 rows; lane c owns channel c of its row.
__global__ __launch_bounds__(256) void k_lstm(const float* __restrict__ zx,
    const float* __restrict__ wh,
    const float* __restrict__ w1, const float* __restrict__ b1,
    const float* __restrict__ w2, const float* __restrict__ b2,
    float* __restrict__ out){
  int tid = threadIdx.x;
  int sub = (tid>>5)&1, c = tid&31;
  int row = blockIdx.x*8 + (tid>>5);   // < 8000
  int b = row/NN, n = row%NN;
  int base = sub<<5;
  float wr0[32], wr1[32], wr2[32], wr3[32];
  #pragma unroll
  for(int i=0;i<32;i++){
    wr0[i]=wh[i*128 + c];
    wr1[i]=wh[i*128 + 32 + c];
    wr2[i]=wh[i*128 + 64 + c];
    wr3[i]=wh[i*128 + 96 + c];
  }
  const float* zr = zx + (size_t)row*TT*128;
  float h=0.f, cs=0.f;
  float p0=zr[c], p1=zr[32+c], p2=zr[64+c], p3=zr[96+c];
  for(int t=0;t<TT;t++){
    float z0=p0, z1=p1, z2=p2, z3=p3;
    if(t+1<TT){
      const float* qq = zr+(size_t)(t+1)*128;
      p0=qq[c]; p1=qq[32+c]; p2=qq[64+c]; p3=qq[96+c];
    }
    #pragma unroll
    for(int i=0;i<32;i++){
      float hv = __shfl(h, base+i, 64);
      z0 = fmaf(hv, wr0[i], z0);
      z1 = fmaf(hv, wr1[i], z1);
      z2 = fmaf(hv, wr2[i], z2);
      z3 = fmaf(hv, wr3[i], z3);
    }
    float ig = sigmoidf_(z0);
    float fg = sigmoidf_(z1);
    float gg = tanhf_(z2);
    float og = sigmoidf_(z3);
    cs = fg*cs + ig*gg;
    h = og*tanhf_(cs);
  }
  float t1 = b1[c];
  #pragma unroll
  for(int i=0;i<32;i++){ float hv=__shfl(h, base+i, 64); t1 = fmaf(hv, w1[i*32+c], t1); }
  t1 = siluf_(t1);
  float y = (c<PREDN)? b2[c] : 0.f;
  #pragma unroll
  for(int i=0;i<32;i++){
    float tv=__shfl(t1, base+i, 64);
    if(c<PREDN) y = fmaf(tv, w2[i*PREDN+c], y);
  }
  if(c<PREDN) out[((size_t)b*PREDN + c)*NN + n] = y;
}

extern "C" void kernel_launch(void* const* d_in, const int* in_sizes, int n_in,
                              void* d_out, int out_size, void* d_ws, size_t ws_size,
                              hipStream_t stream) {
  const float* x       = (const float*)d_in[0];
  const float* xraw    = (const float*)d_in[1];
  const float* W       = (const float*)d_in[3];
  const int*   members = (const int*)d_in[4];
  const int*   centers = (const int*)d_in[5];
  const int*   offsets = (const int*)d_in[6];
  const float* ipw     = (const float*)d_in[7];
  const float* ipb     = (const float*)d_in[8];
  const float* cw      = (const float*)d_in[9];
  const float* cb      = (const float*)d_in[10];
  const float* wx      = (const float*)d_in[11];
  const float* wh      = (const float*)d_in[12];
  const float* lb      = (const float*)d_in[13];
  const float* w1      = (const float*)d_in[14];
  const float* b1      = (const float*)d_in[15];
  const float* w2      = (const float*)d_in[16];
  const float* b2      = (const float*)d_in[17];
  float* out = (float*)d_out;

  float* zx   = (float*)d_ws;                 // 24,576,000 floats
  float* Wd   = zx + 24576000;                // 8,000
  float* dvi  = Wd + 8000;                    // 8,000
  int* edge_nodes = (int*)(dvi + 8000);       // 21,000
  int* edge_cnt   = edge_nodes + 21000;       // 1,000
  int* node_off   = edge_cnt + 1000;          // 1,002
  int* node_edges = node_off + 1002;          // 21,000

  k_prep<<<1, 1024, 0, stream>>>(members, centers, offsets,
                                 edge_nodes, edge_cnt, node_off, node_edges);
  k_simf<<<BB, 1024, 0, stream>>>(xraw, W, members, centers, offsets, Wd);
  k_dv<<<(BB*NN+255)/256, 256, 0, stream>>>(Wd, node_off, node_edges, dvi);
  k_slice<<<BB*TT, 1024, 0, stream>>>(x, ipw, ipb, dvi, Wd,
                                      edge_nodes, edge_cnt, node_off, node_edges,
                                      cw, cb, wx, lb, zx);
  k_lstm<<<(BB*NN)/8, 256, 0, stream>>>(zx, wh, w1, b1, w2, b2, out);
}

// Round 5
// 457.472 us; speedup vs baseline: 1.5801x; 1.1979x over previous
//
#include <hip/hip_runtime.h>
#include <hip/hip_bf16.h>
#include <math.h>

// Problem constants (SingleHyperTKAN)
#define BB 8
#define TT 24
#define NN 1000
#define EE 1000
#define DEG 20
#define FIN 16
#define CRAW 8
#define DM 32
#define HCN 32
#define TKN 32
#define PREDN 12
#define LAMF 0.3f
#define EPSF 1e-8f

typedef float f4 __attribute__((ext_vector_type(4)));

__device__ __forceinline__ float sigmoidf_(float x){ return 1.f/(1.f+__expf(-x)); }
__device__ __forceinline__ float siluf_(float x){ return x/(1.f+__expf(-x)); }
__device__ __forceinline__ float tanhf_(float x){
  float xx = fminf(fmaxf(x,-15.f),15.f);
  float e = __expf(2.f*xx);
  return (e-1.f)/(e+1.f);
}

// ============ k_prep: dedup edges (+0-pad) + node degree + scan + CSR ====
__global__ __launch_bounds__(1024) void k_prep(
    const int* __restrict__ members, const int* __restrict__ centers,
    const int* __restrict__ offsets,
    int* __restrict__ edge_nodes, int* __restrict__ edge_cnt,
    int* __restrict__ node_off, int* __restrict__ node_edges)
{
  __shared__ int deg[NN];
  __shared__ int cur[NN];
  __shared__ int offs[NN+1];
  __shared__ int buf[1024];
  int tid = threadIdx.x;
  for(int i=tid;i<NN;i+=1024){ deg[i]=0; cur[i]=0; }
  __syncthreads();
  int e = tid;
  int cnt = 0;
  if(e<EE){
    int st=offsets[e], en=offsets[e+1];
    int c=centers[e];
    edge_nodes[e*(DEG+1)+0]=c;
    atomicAdd(&deg[c],1);
    cnt=1;
    for(int k=st;k<en;k++){
      int m=members[k];
      bool dup=(m==c);
      for(int k2=st;k2<k && !dup;k2++) if(members[k2]==m) dup=true;
      if(!dup){
        edge_nodes[e*(DEG+1)+cnt]=m;
        atomicAdd(&deg[m],1);
        cnt++;
      }
    }
    edge_cnt[e]=cnt;
    for(int j=cnt;j<DEG+1;j++) edge_nodes[e*(DEG+1)+j]=0;   // pad: safe gather
  }
  __syncthreads();
  buf[tid] = (tid<NN)? deg[tid] : 0;
  __syncthreads();
  for(int d=1;d<1024;d<<=1){
    int v = (tid>=d)? buf[tid-d] : 0;
    __syncthreads();
    buf[tid]+=v;
    __syncthreads();
  }
  if(tid==0) offs[0]=0;
  if(tid<NN) offs[tid+1]=buf[tid];
  __syncthreads();
  if(tid<=NN) node_off[tid]=offs[tid];
  if(e<EE){
    for(int j=0;j<cnt;j++){
      int n = edge_nodes[e*(DEG+1)+j];
      int pos = atomicAdd(&cur[n],1);
      node_edges[offs[n]+pos] = e;
    }
  }
}

// ============ k_feat: mean/std over T, coalesced (n,c) ====
__global__ void k_feat(const float* __restrict__ xraw, float* __restrict__ feat){
  int tid = threadIdx.x;
  int c = tid & 7, nloc = tid >> 3;
  int row = blockIdx.x*32 + nloc;          // (b*N+n) < 8000
  if (row >= BB*NN) return;
  int b = row/NN, n = row%NN;
  float s=0.f, s2=0.f;
  for (int t=0;t<TT;t++){
    float vv = xraw[(((size_t)(b*TT+t)*NN + n)*CRAW) + c];
    s += vv; s2 += vv*vv;
  }
  float m = s*(1.f/TT);
  float var = fmaxf(s2*(1.f/TT) - m*m, 0.f);
  feat[(size_t)row*16 + c]     = m;
  feat[(size_t)row*16 + 8 + c] = sqrtf(var);
}

// ============ k_sim1: mean_sim[b,e] ; 125 blocks x 64 ====
__global__ __launch_bounds__(64) void k_sim1(
    const float* __restrict__ feat,
    const int* __restrict__ members, const int* __restrict__ centers,
    const int* __restrict__ offsets, float* __restrict__ ms)
{
  int idx = blockIdx.x*64 + threadIdx.x;   // (b*EE+e) < 8000
  if(idx >= BB*EE) return;
  int b = idx/EE, e = idx%EE;
  const float* fb = feat + (size_t)b*NN*16;
  int st=offsets[e], en=offsets[e+1];
  int ci=centers[e];
  float cf[16]; float nc=0.f;
  const f4* cp = (const f4*)(fb + ci*16);
  #pragma unroll
  for(int k=0;k<4;k++){
    f4 v = cp[k];
    #pragma unroll
    for(int c=0;c<4;c++){ cf[4*k+c]=v[c]; nc = fmaf(v[c],v[c],nc); }
  }
  nc = sqrtf(nc);
  float acc=0.f;
  for(int k=st;k<en;k++){
    int m=members[k];
    const f4* mp = (const f4*)(fb + m*16);
    float dot=0.f, nm=0.f;
    #pragma unroll
    for(int kk=0;kk<4;kk++){
      f4 v = mp[kk];
      #pragma unroll
      for(int c=0;c<4;c++){ dot = fmaf(v[c], cf[4*kk+c], dot); nm = fmaf(v[c],v[c],nm); }
    }
    float sim = dot/(sqrtf(nm)*nc + EPSF);
    acc += fminf(fmaxf(sim,0.f),1.f);
  }
  ms[idx] = acc / fmaxf((float)(en-st),1.f);
}

// ============ k_sim2: minmax over e + Wd ; 8 blocks x 1024 ====
__global__ __launch_bounds__(1024) void k_sim2(
    const float* __restrict__ ms, const float* __restrict__ W,
    float* __restrict__ Wd)
{
  __shared__ float red1[1024], red2[1024];
  int b = blockIdx.x;
  int tid = threadIdx.x;
  float msv = (tid<EE)? ms[b*EE+tid] : 0.f;
  red1[tid]=(tid<EE)? msv : 1e30f;
  red2[tid]=(tid<EE)? msv : -1e30f;
  __syncthreads();
  for(int s=512;s>0;s>>=1){
    if(tid<s){
      red1[tid]=fminf(red1[tid],red1[tid+s]);
      red2[tid]=fmaxf(red2[tid],red2[tid+s]);
    }
    __syncthreads();
  }
  if(tid<EE){
    float msn=(msv-red1[0])/(red2[0]-red1[0]+EPSF);
    Wd[b*EE+tid]=W[tid]*(1.f+LAMF*msn);
  }
}

// ============ k_dv ====
__global__ void k_dv(const float* __restrict__ Wd, const int* __restrict__ node_off,
                     const int* __restrict__ node_edges, float* __restrict__ dvi){
  int idx = blockIdx.x*blockDim.x + threadIdx.x;
  if (idx>=BB*NN) return;
  int b = idx/NN, n = idx%NN;
  int st=node_off[n], en=node_off[n+1];
  float dv=0.f;
  for(int k=st;k<en;k++) dv += Wd[b*EE + node_edges[k]];
  dvi[idx] = rsqrtf(fmaxf(dv, EPSF));
}

// ============ k_slice: per-(b,t) fused z -> v -> h2 -> conv -> hc ====
// grid 192, block 1024. zbuf XOR-swizzled: quad index q ^= (row&7).
__global__ __launch_bounds__(1024) void k_slice(
    const float* __restrict__ x,
    const float* __restrict__ ipw, const float* __restrict__ ipb,
    const float* __restrict__ dvi, const float* __restrict__ Wd,
    const int* __restrict__ edge_nodes, const int* __restrict__ edge_cnt,
    const int* __restrict__ node_off, const int* __restrict__ node_edges,
    const float* __restrict__ cw, const float* __restrict__ cb,
    float* __restrict__ hc_out)
{
  __shared__ f4 zbuf[NN*8];         // 128000 B
  __shared__ float ipws[FIN*32];    // 2 KB
  __shared__ f4 cws4[DM*8];         // 4 KB : cw[i][4q..4q+3]
  __shared__ float wde[EE];         // 4 KB
  __shared__ int   cnts[EE];        // 4 KB
  __shared__ float ipbs[32], cbs[32];

  int tid = threadIdx.x;
  int bt  = blockIdx.x;
  int b = bt / TT, t = bt % TT;

  for(int i=tid;i<FIN*32;i+=1024) ipws[i]=ipw[i];
  for(int i=tid;i<DM*8;i+=1024) cws4[i]=((const f4*)cw)[i];
  for(int e=tid;e<EE;e+=1024){
    int c = edge_cnt[e];
    cnts[e]=c;
    wde[e]=Wd[b*EE+e]/(float)c;
  }
  if(tid<32){ ipbs[tid]=ipb[tid]; cbs[tid]=cb[tid]; }
  __syncthreads();

  const float* xb  = x + (size_t)bt*NN*FIN;
  const float* dvb = dvi + b*NN;
  float* zs = (float*)zbuf;

  // ---- Phase A: z[r,f] = dvi * (x @ ipw + ipb), swizzled write ----
  {
    int g = tid>>5, f = tid&31;
    for(int p=0;p<32;p++){
      int r = p*32+g;
      if(r<NN){
        const f4* x4 = (const f4*)(xb + r*FIN);
        float acc = ipbs[f];
        #pragma unroll
        for(int k=0;k<4;k++){
          f4 xv = x4[k];
          acc = fmaf(xv[0], ipws[(4*k+0)*32+f], acc);
          acc = fmaf(xv[1], ipws[(4*k+1)*32+f], acc);
          acc = fmaf(xv[2], ipws[(4*k+2)*32+f], acc);
          acc = fmaf(xv[3], ipws[(4*k+3)*32+f], acc);
        }
        zs[r*32 + (((f>>2)^(r&7))<<2) + (f&3)] = dvb[r]*acc;
      }
    }
  }
  __syncthreads();

  // ---- Phase B: v[e,quad] = wde * sum_{m in e} z[m,quad] ----
  int grp = tid>>3, q = tid&7;
  f4 vreg[8];
  #pragma unroll
  for(int p=0;p<8;p++){
    int e = p*128 + grp;
    f4 acc = (f4)0.f;
    if(e<EE){
      int cnt = cnts[e];
      const int* enp = edge_nodes + e*(DEG+1);
      int idx[DEG+1];
      #pragma unroll
      for(int j=0;j<DEG+1;j++) idx[j]=enp[j];
      #pragma unroll
      for(int j=0;j<DEG+1;j++){
        f4 v = zbuf[idx[j]*8 + (q ^ (idx[j]&7))];
        if(j<cnt) acc += v;
      }
      acc *= wde[e];
    }
    vreg[p]=acc;
  }
  __syncthreads();
  #pragma unroll
  for(int p=0;p<8;p++){
    int e = p*128 + grp;
    if(e<EE) zbuf[e*8 + (q^(e&7))] = vreg[p];
  }
  __syncthreads();

  // ---- Phase D: h2 gather -> conv+silu (shfl) -> hc global ----
  int lanew = tid&63, grpw = lanew>>3;
  for(int p=0;p<8;p++){
    int n = p*128 + grp;
    f4 acc = (f4)0.f;
    int st=0, en=0;
    if(n<NN){ st=node_off[n]; en=node_off[n+1]; }
    for(int j=st;j<en;j+=4){
      #pragma unroll
      for(int k=0;k<4;k++){
        int jj = (j+k<en)? j+k : st;
        int e2 = node_edges[jj];
        f4 v = zbuf[e2*8 + (q ^ (e2&7))];
        if(j+k<en) acc += v;
      }
    }
    float dvn = (n<NN)? dvb[n] : 0.f;
    acc *= dvn;          // h2 quad
    // conv 32->32 via intra-group shfl
    f4 hcq;
    #pragma unroll
    for(int c=0;c<4;c++) hcq[c]=cbs[q*4+c];
    #pragma unroll
    for(int i=0;i<32;i++){
      float h2i = __shfl(acc[i&3], grpw*8 + (i>>2), 64);
      f4 w = cws4[i*8+q];
      hcq += h2i * w;
    }
    #pragma unroll
    for(int c=0;c<4;c++) hcq[c]=siluf_(hcq[c]);
    if(n<NN) ((f4*)hc_out)[ ((size_t)(b*NN+n)*TT + t)*8 + q ] = hcq;
  }
}

// ============ k_lstm: serial T + folded wx projection + fused head ====
// block 256 = 4 waves = 8 rows; lane c owns channel c. wh+wx in VGPRs.
__global__ __launch_bounds__(256) void k_lstm(const float* __restrict__ hc,
    const float* __restrict__ wh, const float* __restrict__ wx,
    const float* __restrict__ lb,
    const float* __restrict__ w1, const float* __restrict__ b1,
    const float* __restrict__ w2, const float* __restrict__ b2,
    float* __restrict__ out){
  int tid = threadIdx.x;
  int sub = (tid>>5)&1, c = tid&31;
  int row = blockIdx.x*8 + (tid>>5);   // < 8000
  int b = row/NN, n = row%NN;
  int base = sub<<5;
  float wr0[32], wr1[32], wr2[32], wr3[32];
  float xr0[32], xr1[32], xr2[32], xr3[32];
  #pragma unroll
  for(int i=0;i<32;i++){
    wr0[i]=wh[i*128 + c];
    wr1[i]=wh[i*128 + 32 + c];
    wr2[i]=wh[i*128 + 64 + c];
    wr3[i]=wh[i*128 + 96 + c];
    xr0[i]=wx[i*128 + c];
    xr1[i]=wx[i*128 + 32 + c];
    xr2[i]=wx[i*128 + 64 + c];
    xr3[i]=wx[i*128 + 96 + c];
  }
  float l0=lb[c], l1=lb[32+c], l2=lb[64+c], l3=lb[96+c];
  const float* zr = hc + (size_t)row*TT*32;
  float h=0.f, cs=0.f;
  float hcv = zr[c];
  for(int t=0;t<TT;t++){
    float cur = hcv;
    if(t+1<TT) hcv = zr[(size_t)(t+1)*32 + c];
    float z0=l0, z1=l1, z2=l2, z3=l3;
    #pragma unroll
    for(int i=0;i<32;i++){
      float hv = __shfl(h,   base+i, 64);
      float hb = __shfl(cur, base+i, 64);
      z0 = fmaf(hv, wr0[i], fmaf(hb, xr0[i], z0));
      z1 = fmaf(hv, wr1[i], fmaf(hb, xr1[i], z1));
      z2 = fmaf(hv, wr2[i], fmaf(hb, xr2[i], z2));
      z3 = fmaf(hv, wr3[i], fmaf(hb, xr3[i], z3));
    }
    float ig = sigmoidf_(z0);
    float fg = sigmoidf_(z1);
    float gg = tanhf_(z2);
    float og = sigmoidf_(z3);
    cs = fg*cs + ig*gg;
    h = og*tanhf_(cs);
  }
  float t1 = b1[c];
  #pragma unroll
  for(int i=0;i<32;i++){ float hv=__shfl(h, base+i, 64); t1 = fmaf(hv, w1[i*32+c], t1); }
  t1 = siluf_(t1);
  float y = (c<PREDN)? b2[c] : 0.f;
  #pragma unroll
  for(int i=0;i<32;i++){
    float tv=__shfl(t1, base+i, 64);
    if(c<PREDN) y = fmaf(tv, w2[i*PREDN+c], y);
  }
  if(c<PREDN) out[((size_t)b*PREDN + c)*NN + n] = y;
}

extern "C" void kernel_launch(void* const* d_in, const int* in_sizes, int n_in,
                              void* d_out, int out_size, void* d_ws, size_t ws_size,
                              hipStream_t stream) {
  const float* x       = (const float*)d_in[0];
  const float* xraw    = (const float*)d_in[1];
  const float* W       = (const float*)d_in[3];
  const int*   members = (const int*)d_in[4];
  const int*   centers = (const int*)d_in[5];
  const int*   offsets = (const int*)d_in[6];
  const float* ipw     = (const float*)d_in[7];
  const float* ipb     = (const float*)d_in[8];
  const float* cw      = (const float*)d_in[9];
  const float* cb      = (const float*)d_in[10];
  const float* wx      = (const float*)d_in[11];
  const float* wh      = (const float*)d_in[12];
  const float* lb      = (const float*)d_in[13];
  const float* w1      = (const float*)d_in[14];
  const float* b1      = (const float*)d_in[15];
  const float* w2      = (const float*)d_in[16];
  const float* b2      = (const float*)d_in[17];
  float* out = (float*)d_out;

  float* hc   = (float*)d_ws;                 // 6,144,000 floats
  float* feat = hc + 6144000;                 // 128,000
  float* ms   = feat + 128000;                // 8,000
  float* Wd   = ms + 8000;                    // 8,000
  float* dvi  = Wd + 8000;                    // 8,000
  int* edge_nodes = (int*)(dvi + 8000);       // 21,000
  int* edge_cnt   = edge_nodes + 21000;       // 1,000
  int* node_off   = edge_cnt + 1000;          // 1,001
  int* node_edges = node_off + 1001;          // 21,000

  k_prep<<<1, 1024, 0, stream>>>(members, centers, offsets,
                                 edge_nodes, edge_cnt, node_off, node_edges);
  k_feat<<<250, 256, 0, stream>>>(xraw, feat);
  k_sim1<<<125, 64, 0, stream>>>(feat, members, centers, offsets, ms);
  k_sim2<<<BB, 1024, 0, stream>>>(ms, W, Wd);
  k_dv<<<(BB*NN+255)/256, 256, 0, stream>>>(Wd, node_off, node_edges, dvi);
  k_slice<<<BB*TT, 1024, 0, stream>>>(x, ipw, ipb, dvi, Wd,
                                      edge_nodes, edge_cnt, node_off, node_edges,
                                      cw, cb, hc);
  k_lstm<<<(BB*NN)/8, 256, 0, stream>>>(hc, wh, wx, lb, w1, b1, w2, b2, out);
}

// Round 6
// 349.708 us; speedup vs baseline: 2.0670x; 1.3082x over previous
//
#include <hip/hip_runtime.h>
#include <hip/hip_bf16.h>
#include <math.h>

// Problem constants (SingleHyperTKAN)
#define BB 8
#define TT 24
#define NN 1000
#define EE 1000
#define DEG 20
#define FIN 16
#define CRAW 8
#define DM 32
#define HCN 32
#define TKN 32
#define PREDN 12
#define LAMF 0.3f
#define EPSF 1e-8f

typedef float f4 __attribute__((ext_vector_type(4)));

__device__ __forceinline__ float sigmoidf_(float x){ return 1.f/(1.f+__expf(-x)); }
__device__ __forceinline__ float siluf_(float x){ return x/(1.f+__expf(-x)); }
__device__ __forceinline__ float tanhf_(float x){
  float xx = fminf(fmaxf(x,-15.f),15.f);
  float e = __expf(2.f*xx);
  return (e-1.f)/(e+1.f);
}

// ============ k_prep: dedup edges (+0-pad) + node degree + scan + CSR ====
// offsets are always e*20 (setup), so member list is exactly DEG long.
__global__ __launch_bounds__(1024) void k_prep(
    const int* __restrict__ members, const int* __restrict__ centers,
    const int* __restrict__ offsets,
    int* __restrict__ edge_nodes, int* __restrict__ edge_cnt,
    int* __restrict__ node_off, int* __restrict__ node_edges)
{
  __shared__ int deg[NN];
  __shared__ int cur[NN];
  __shared__ int offs[NN+1];
  __shared__ int buf[1024];
  int tid = threadIdx.x;
  for(int i=tid;i<NN;i+=1024){ deg[i]=0; cur[i]=0; }
  __syncthreads();
  int e = tid;
  int cnt = 0;
  if(e<EE){
    int st=offsets[e], en=offsets[e+1];
    int c=centers[e];
    int mem[DEG];
    #pragma unroll
    for(int k=0;k<DEG;k++) mem[k] = (st+k<en)? members[st+k] : -1;
    edge_nodes[e*(DEG+1)+0]=c;
    atomicAdd(&deg[c],1);
    cnt=1;
    #pragma unroll
    for(int k=0;k<DEG;k++){
      int m = mem[k];
      bool dup = (m==c) | (m<0);
      #pragma unroll
      for(int k2=0;k2<DEG;k2++) if(k2<k && mem[k2]==m) dup=true;
      if(!dup){
        edge_nodes[e*(DEG+1)+cnt]=m;
        atomicAdd(&deg[m],1);
        cnt++;
      }
    }
    edge_cnt[e]=cnt;
    for(int j=cnt;j<DEG+1;j++) edge_nodes[e*(DEG+1)+j]=0;   // pad: safe gather
  }
  __syncthreads();
  buf[tid] = (tid<NN)? deg[tid] : 0;
  __syncthreads();
  for(int d=1;d<1024;d<<=1){
    int v = (tid>=d)? buf[tid-d] : 0;
    __syncthreads();
    buf[tid]+=v;
    __syncthreads();
  }
  if(tid==0) offs[0]=0;
  if(tid<NN) offs[tid+1]=buf[tid];
  __syncthreads();
  if(tid<=NN) node_off[tid]=offs[tid];
  if(e<EE){
    for(int j=0;j<cnt;j++){
      int n = edge_nodes[e*(DEG+1)+j];
      int pos = atomicAdd(&cur[n],1);
      node_edges[offs[n]+pos] = e;
    }
  }
}

// ============ k_feat: mean/std over T, coalesced (n,c) ====
__global__ void k_feat(const float* __restrict__ xraw, float* __restrict__ feat){
  int tid = threadIdx.x;
  int c = tid & 7, nloc = tid >> 3;
  int row = blockIdx.x*32 + nloc;          // (b*N+n) < 8000
  if (row >= BB*NN) return;
  int b = row/NN, n = row%NN;
  float s=0.f, s2=0.f;
  for (int t=0;t<TT;t++){
    float vv = xraw[(((size_t)(b*TT+t)*NN + n)*CRAW) + c];
    s += vv; s2 += vv*vv;
  }
  float m = s*(1.f/TT);
  float var = fmaxf(s2*(1.f/TT) - m*m, 0.f);
  feat[(size_t)row*16 + c]     = m;
  feat[(size_t)row*16 + 8 + c] = sqrtf(var);
}

// ============ k_sim1: mean_sim[b,e] ; 4-lane teams, 125 blocks x 256 ====
__global__ __launch_bounds__(256) void k_sim1(
    const float* __restrict__ feat,
    const int* __restrict__ members, const int* __restrict__ centers,
    const int* __restrict__ offsets, float* __restrict__ ms)
{
  int tid = threadIdx.x;
  int lane2 = tid & 3;
  int task = blockIdx.x*64 + (tid>>2);     // (b*EE+e) < 8000
  if(task >= BB*EE) return;
  int b = task/EE, e = task%EE;
  const float* fb = feat + (size_t)b*NN*16;
  int st=offsets[e], en=offsets[e+1];
  int ci=centers[e];
  float cf[16]; float nc=0.f;
  const f4* cp = (const f4*)(fb + ci*16);
  #pragma unroll
  for(int k=0;k<4;k++){
    f4 v = cp[k];
    #pragma unroll
    for(int c=0;c<4;c++){ cf[4*k+c]=v[c]; nc = fmaf(v[c],v[c],nc); }
  }
  nc = sqrtf(nc);
  float acc=0.f;
  for(int k=st+lane2;k<en;k+=4){
    int m=members[k];
    const f4* mp = (const f4*)(fb + m*16);
    float dot=0.f, nm=0.f;
    #pragma unroll
    for(int kk=0;kk<4;kk++){
      f4 v = mp[kk];
      #pragma unroll
      for(int c=0;c<4;c++){ dot = fmaf(v[c], cf[4*kk+c], dot); nm = fmaf(v[c],v[c],nm); }
    }
    float sim = dot/(sqrtf(nm)*nc + EPSF);
    acc += fminf(fmaxf(sim,0.f),1.f);
  }
  acc += __shfl_xor(acc, 1, 64);
  acc += __shfl_xor(acc, 2, 64);
  if(lane2==0) ms[task] = acc / fmaxf((float)(en-st),1.f);
}

// ============ k_sim2dv: minmax + Wd + dvi ; 8 blocks x 1024 ====
__global__ __launch_bounds__(1024) void k_sim2dv(
    const float* __restrict__ ms, const float* __restrict__ W,
    const int* __restrict__ node_off, const int* __restrict__ node_edges,
    float* __restrict__ Wd, float* __restrict__ dvi)
{
  __shared__ float red1[1024], red2[1024];
  __shared__ float wdl[EE];
  int b = blockIdx.x;
  int tid = threadIdx.x;
  float msv = (tid<EE)? ms[b*EE+tid] : 0.f;
  red1[tid]=(tid<EE)? msv : 1e30f;
  red2[tid]=(tid<EE)? msv : -1e30f;
  __syncthreads();
  for(int s=512;s>0;s>>=1){
    if(tid<s){
      red1[tid]=fminf(red1[tid],red1[tid+s]);
      red2[tid]=fmaxf(red2[tid],red2[tid+s]);
    }
    __syncthreads();
  }
  if(tid<EE){
    float msn=(msv-red1[0])/(red2[0]-red1[0]+EPSF);
    float w = W[tid]*(1.f+LAMF*msn);
    Wd[b*EE+tid]=w;
    wdl[tid]=w;
  }
  __syncthreads();
  if(tid<NN){
    int st=node_off[tid], en=node_off[tid+1];
    float dv=0.f;
    for(int k=st;k<en;k++) dv += wdl[node_edges[k]];
    dvi[b*NN+tid] = rsqrtf(fmaxf(dv, EPSF));
  }
}

// ============ k_slice: per-(b,t) fused z -> v -> h2 -> conv -> hc ====
// grid 192, block 1024. zbuf XOR-swizzled: quad index q ^= (row&7).
__global__ __launch_bounds__(1024) void k_slice(
    const float* __restrict__ x,
    const float* __restrict__ ipw, const float* __restrict__ ipb,
    const float* __restrict__ dvi, const float* __restrict__ Wd,
    const int* __restrict__ edge_nodes, const int* __restrict__ edge_cnt,
    const int* __restrict__ node_off, const int* __restrict__ node_edges,
    const float* __restrict__ cw, const float* __restrict__ cb,
    float* __restrict__ hc_out)
{
  __shared__ f4 zbuf[NN*8];         // 128000 B
  __shared__ float ipws[FIN*32];    // 2 KB
  __shared__ f4 cws4[DM*8];         // 4 KB : cw[i][4q..4q+3]
  __shared__ float wde[EE];         // 4 KB
  __shared__ int   cnts[EE];        // 4 KB
  __shared__ float ipbs[32], cbs[32];

  int tid = threadIdx.x;
  int bt  = blockIdx.x;
  int b = bt / TT, t = bt % TT;

  for(int i=tid;i<FIN*32;i+=1024) ipws[i]=ipw[i];
  for(int i=tid;i<DM*8;i+=1024) cws4[i]=((const f4*)cw)[i];
  for(int e=tid;e<EE;e+=1024){
    int c = edge_cnt[e];
    cnts[e]=c;
    wde[e]=Wd[b*EE+e]/(float)c;
  }
  if(tid<32){ ipbs[tid]=ipb[tid]; cbs[tid]=cb[tid]; }
  __syncthreads();

  const float* xb  = x + (size_t)bt*NN*FIN;
  const float* dvb = dvi + b*NN;
  float* zs = (float*)zbuf;

  // ---- Phase A: z[r,f] = dvi * (x @ ipw + ipb), swizzled write ----
  {
    int g = tid>>5, f = tid&31;
    for(int p=0;p<32;p++){
      int r = p*32+g;
      if(r<NN){
        const f4* x4 = (const f4*)(xb + r*FIN);
        float acc = ipbs[f];
        #pragma unroll
        for(int k=0;k<4;k++){
          f4 xv = x4[k];
          acc = fmaf(xv[0], ipws[(4*k+0)*32+f], acc);
          acc = fmaf(xv[1], ipws[(4*k+1)*32+f], acc);
          acc = fmaf(xv[2], ipws[(4*k+2)*32+f], acc);
          acc = fmaf(xv[3], ipws[(4*k+3)*32+f], acc);
        }
        zs[r*32 + (((f>>2)^(r&7))<<2) + (f&3)] = dvb[r]*acc;
      }
    }
  }
  __syncthreads();

  // ---- Phase B: v[e,quad] = wde * sum_{m in e} z[m,quad] ----
  int grp = tid>>3, q = tid&7;
  f4 vreg[8];
  #pragma unroll
  for(int p=0;p<8;p++){
    int e = p*128 + grp;
    f4 acc = (f4)0.f;
    if(e<EE){
      int cnt = cnts[e];
      const int* enp = edge_nodes + e*(DEG+1);
      int idx[DEG+1];
      #pragma unroll
      for(int j=0;j<DEG+1;j++) idx[j]=enp[j];
      #pragma unroll
      for(int j=0;j<DEG+1;j++){
        f4 v = zbuf[idx[j]*8 + (q ^ (idx[j]&7))];
        if(j<cnt) acc += v;
      }
      acc *= wde[e];
    }
    vreg[p]=acc;
  }
  __syncthreads();
  #pragma unroll
  for(int p=0;p<8;p++){
    int e = p*128 + grp;
    if(e<EE) zbuf[e*8 + (q^(e&7))] = vreg[p];
  }
  __syncthreads();

  // ---- Phase D: h2 gather -> conv+silu (shfl) -> hc global ----
  int lanew = tid&63, grpw = lanew>>3;
  for(int p=0;p<8;p++){
    int n = p*128 + grp;
    f4 acc = (f4)0.f;
    int st=0, en=0;
    if(n<NN){ st=node_off[n]; en=node_off[n+1]; }
    for(int j=st;j<en;j+=4){
      #pragma unroll
      for(int k=0;k<4;k++){
        int jj = (j+k<en)? j+k : st;
        int e2 = node_edges[jj];
        f4 v = zbuf[e2*8 + (q ^ (e2&7))];
        if(j+k<en) acc += v;
      }
    }
    float dvn = (n<NN)? dvb[n] : 0.f;
    acc *= dvn;          // h2 quad
    // conv 32->32 via intra-group shfl
    f4 hcq;
    #pragma unroll
    for(int c=0;c<4;c++) hcq[c]=cbs[q*4+c];
    #pragma unroll
    for(int i=0;i<32;i++){
      float h2i = __shfl(acc[i&3], grpw*8 + (i>>2), 64);
      f4 w = cws4[i*8+q];
      hcq += h2i * w;
    }
    #pragma unroll
    for(int c=0;c<4;c++) hcq[c]=siluf_(hcq[c]);
    if(n<NN) ((f4*)hc_out)[ ((size_t)(b*NN+n)*TT + t)*8 + q ] = hcq;
  }
}

// ============ k_lstm v2: in-LDS zx precompute + slim serial recurrence ====
// block 256 = 4 waves = 8 rows. Phase1: zx = hc@wx+lb (parallel). Phase2: serial.
__global__ __launch_bounds__(256,1) void k_lstm(const float* __restrict__ hc,
    const float* __restrict__ wh, const float* __restrict__ wx,
    const float* __restrict__ lb,
    const float* __restrict__ w1, const float* __restrict__ b1,
    const float* __restrict__ w2, const float* __restrict__ b2,
    float* __restrict__ out){
  __shared__ float zxl[8*TT*128];   // 98304 B
  __shared__ float hcl[8*TT*32];    // 24576 B
  int tid = threadIdx.x;
  int row0 = blockIdx.x*8;
  int q = tid&31, r = tid>>5;       // r in [0,8): row index; q: quad/channel

  // stage hc slice (contiguous 6144 floats = 1536 f4)
  {
    const f4* hcg = (const f4*)(hc + (size_t)row0*TT*32);
    f4* hcl4 = (f4*)hcl;
    #pragma unroll
    for(int k=0;k<6;k++) hcl4[tid + k*256] = hcg[tid + k*256];
  }
  // wx columns in registers: thread owns output quad q (cols 4q..4q+3)
  f4 wxr[32];
  #pragma unroll
  for(int i=0;i<32;i++) wxr[i] = ((const f4*)wx)[i*32 + q];
  f4 lbq = ((const f4*)lb)[q];
  __syncthreads();

  // ---- Phase 1: zx[r][t][4q..4q+3] = lb + hc[r][t][:] @ wx ----
  for(int t=0;t<TT;t++){
    f4 acc = lbq;
    const float* hrow = &hcl[(r*TT+t)*32];
    #pragma unroll
    for(int i=0;i<32;i++) acc += hrow[i]*wxr[i];
    *(f4*)&zxl[(r*TT+t)*128 + 4*q] = acc;
  }
  __syncthreads();

  // ---- Phase 2: serial recurrence; lane c = q owns channel c of row r ----
  int sub = r&1;
  int base = sub<<5;
  int c = q;
  float wr0[32], wr1[32], wr2[32], wr3[32];
  #pragma unroll
  for(int i=0;i<32;i++){
    wr0[i]=wh[i*128 + c];
    wr1[i]=wh[i*128 + 32 + c];
    wr2[i]=wh[i*128 + 64 + c];
    wr3[i]=wh[i*128 + 96 + c];
  }
  const float* zrow = &zxl[r*TT*128];
  float h=0.f, cs=0.f;
  float p0=zrow[c], p1=zrow[32+c], p2=zrow[64+c], p3=zrow[96+c];
  for(int t=0;t<TT;t++){
    float z0=p0, z1=p1, z2=p2, z3=p3;
    if(t+1<TT){
      const float* nz = zrow + (t+1)*128;
      p0=nz[c]; p1=nz[32+c]; p2=nz[64+c]; p3=nz[96+c];
    }
    #pragma unroll
    for(int i=0;i<32;i++){
      float hv = __shfl(h, base+i, 64);
      z0 = fmaf(hv, wr0[i], z0);
      z1 = fmaf(hv, wr1[i], z1);
      z2 = fmaf(hv, wr2[i], z2);
      z3 = fmaf(hv, wr3[i], z3);
    }
    float ig = sigmoidf_(z0);
    float fg = sigmoidf_(z1);
    float gg = tanhf_(z2);
    float og = sigmoidf_(z3);
    cs = fg*cs + ig*gg;
    h = og*tanhf_(cs);
  }
  // head
  int row = row0 + r;
  int b = row/NN, n = row%NN;
  float t1 = b1[c];
  #pragma unroll
  for(int i=0;i<32;i++){ float hv=__shfl(h, base+i, 64); t1 = fmaf(hv, w1[i*32+c], t1); }
  t1 = siluf_(t1);
  float y = (c<PREDN)? b2[c] : 0.f;
  #pragma unroll
  for(int i=0;i<32;i++){
    float tv=__shfl(t1, base+i, 64);
    if(c<PREDN) y = fmaf(tv, w2[i*PREDN+c], y);
  }
  if(c<PREDN) out[((size_t)b*PREDN + c)*NN + n] = y;
}

extern "C" void kernel_launch(void* const* d_in, const int* in_sizes, int n_in,
                              void* d_out, int out_size, void* d_ws, size_t ws_size,
                              hipStream_t stream) {
  const float* x       = (const float*)d_in[0];
  const float* xraw    = (const float*)d_in[1];
  const float* W       = (const float*)d_in[3];
  const int*   members = (const int*)d_in[4];
  const int*   centers = (const int*)d_in[5];
  const int*   offsets = (const int*)d_in[6];
  const float* ipw     = (const float*)d_in[7];
  const float* ipb     = (const float*)d_in[8];
  const float* cw      = (const float*)d_in[9];
  const float* cb      = (const float*)d_in[10];
  const float* wx      = (const float*)d_in[11];
  const float* wh      = (const float*)d_in[12];
  const float* lb      = (const float*)d_in[13];
  const float* w1      = (const float*)d_in[14];
  const float* b1      = (const float*)d_in[15];
  const float* w2      = (const float*)d_in[16];
  const float* b2      = (const float*)d_in[17];
  float* out = (float*)d_out;

  float* hc   = (float*)d_ws;                 // 6,144,000 floats
  float* feat = hc + 6144000;                 // 128,000
  float* ms   = feat + 128000;                // 8,000
  float* Wd   = ms + 8000;                    // 8,000
  float* dvi  = Wd + 8000;                    // 8,000
  int* edge_nodes = (int*)(dvi + 8000);       // 21,000
  int* edge_cnt   = edge_nodes + 21000;       // 1,000
  int* node_off   = edge_cnt + 1000;          // 1,001
  int* node_edges = node_off + 1001;          // 21,000

  k_prep<<<1, 1024, 0, stream>>>(members, centers, offsets,
                                 edge_nodes, edge_cnt, node_off, node_edges);
  k_feat<<<250, 256, 0, stream>>>(xraw, feat);
  k_sim1<<<125, 256, 0, stream>>>(feat, members, centers, offsets, ms);
  k_sim2dv<<<BB, 1024, 0, stream>>>(ms, W, node_off, node_edges, Wd, dvi);
  k_slice<<<BB*TT, 1024, 0, stream>>>(x, ipw, ipb, dvi, Wd,
                                      edge_nodes, edge_cnt, node_off, node_edges,
                                      cw, cb, hc);
  k_lstm<<<(BB*NN)/8, 256, 0, stream>>>(hc, wh, wx, lb, w1, b1, w2, b2, out);
}

// Round 7
// 310.588 us; speedup vs baseline: 2.3273x; 1.1260x over previous
//
#include <hip/hip_runtime.h>
#include <hip/hip_bf16.h>
#include <math.h>

// Problem constants (SingleHyperTKAN)
#define BB 8
#define TT 24
#define NN 1000
#define EE 1000
#define DEG 20
#define FIN 16
#define CRAW 8
#define DM 32
#define HCN 32
#define TKN 32
#define PREDN 12
#define LAMF 0.3f
#define EPSF 1e-8f

typedef float f4 __attribute__((ext_vector_type(4)));

__device__ __forceinline__ float sigmoidf_(float x){ return 1.f/(1.f+__expf(-x)); }
__device__ __forceinline__ float siluf_(float x){ return x/(1.f+__expf(-x)); }
__device__ __forceinline__ float tanhf_(float x){
  float xx = fminf(fmaxf(x,-15.f),15.f);
  float e = __expf(2.f*xx);
  return (e-1.f)/(e+1.f);
}
// fast variants (v_rcp_f32, ~1 ulp: margin is 200x)
__device__ __forceinline__ float sigmfast_(float x){
  return __builtin_amdgcn_rcpf(1.f+__expf(-x));
}
__device__ __forceinline__ float tanhfast_(float x){
  float xx = fminf(fmaxf(x,-15.f),15.f);
  float e = __expf(2.f*xx);
  return 1.f - 2.f*__builtin_amdgcn_rcpf(e+1.f);
}

// ============ k_prep: dedup edges (+0-pad) + node degree + scan + CSR ====
__global__ __launch_bounds__(1024) void k_prep(
    const int* __restrict__ members, const int* __restrict__ centers,
    const int* __restrict__ offsets,
    int* __restrict__ edge_nodes, int* __restrict__ edge_cnt,
    int* __restrict__ node_off, int* __restrict__ node_edges)
{
  __shared__ int deg[NN];
  __shared__ int cur[NN];
  __shared__ int offs[NN+1];
  __shared__ int buf[1024];
  int tid = threadIdx.x;
  for(int i=tid;i<NN;i+=1024){ deg[i]=0; cur[i]=0; }
  __syncthreads();
  int e = tid;
  int cnt = 0;
  if(e<EE){
    int st=offsets[e], en=offsets[e+1];
    int c=centers[e];
    int mem[DEG];
    #pragma unroll
    for(int k=0;k<DEG;k++) mem[k] = (st+k<en)? members[st+k] : -1;
    edge_nodes[e*(DEG+1)+0]=c;
    atomicAdd(&deg[c],1);
    cnt=1;
    #pragma unroll
    for(int k=0;k<DEG;k++){
      int m = mem[k];
      bool dup = (m==c) | (m<0);
      #pragma unroll
      for(int k2=0;k2<DEG;k2++) if(k2<k && mem[k2]==m) dup=true;
      if(!dup){
        edge_nodes[e*(DEG+1)+cnt]=m;
        atomicAdd(&deg[m],1);
        cnt++;
      }
    }
    edge_cnt[e]=cnt;
    for(int j=cnt;j<DEG+1;j++) edge_nodes[e*(DEG+1)+j]=0;   // pad: safe gather
  }
  __syncthreads();
  buf[tid] = (tid<NN)? deg[tid] : 0;
  __syncthreads();
  for(int d=1;d<1024;d<<=1){
    int v = (tid>=d)? buf[tid-d] : 0;
    __syncthreads();
    buf[tid]+=v;
    __syncthreads();
  }
  if(tid==0) offs[0]=0;
  if(tid<NN) offs[tid+1]=buf[tid];
  __syncthreads();
  if(tid<=NN) node_off[tid]=offs[tid];
  if(e<EE){
    for(int j=0;j<cnt;j++){
      int n = edge_nodes[e*(DEG+1)+j];
      int pos = atomicAdd(&cur[n],1);
      node_edges[offs[n]+pos] = e;
    }
  }
}

// ============ k_feat: mean/std over T, coalesced (n,c) ====
__global__ void k_feat(const float* __restrict__ xraw, float* __restrict__ feat){
  int tid = threadIdx.x;
  int c = tid & 7, nloc = tid >> 3;
  int row = blockIdx.x*32 + nloc;          // (b*N+n) < 8000
  if (row >= BB*NN) return;
  int b = row/NN, n = row%NN;
  float s=0.f, s2=0.f;
  for (int t=0;t<TT;t++){
    float vv = xraw[(((size_t)(b*TT+t)*NN + n)*CRAW) + c];
    s += vv; s2 += vv*vv;
  }
  float m = s*(1.f/TT);
  float var = fmaxf(s2*(1.f/TT) - m*m, 0.f);
  feat[(size_t)row*16 + c]     = m;
  feat[(size_t)row*16 + 8 + c] = sqrtf(var);
}

// ============ k_sim1: mean_sim[b,e] ; 4-lane teams, 125 blocks x 256 ====
__global__ __launch_bounds__(256) void k_sim1(
    const float* __restrict__ feat,
    const int* __restrict__ members, const int* __restrict__ centers,
    const int* __restrict__ offsets, float* __restrict__ ms)
{
  int tid = threadIdx.x;
  int lane2 = tid & 3;
  int task = blockIdx.x*64 + (tid>>2);     // (b*EE+e) < 8000
  if(task >= BB*EE) return;
  int b = task/EE, e = task%EE;
  const float* fb = feat + (size_t)b*NN*16;
  int st=offsets[e], en=offsets[e+1];
  int ci=centers[e];
  float cf[16]; float nc=0.f;
  const f4* cp = (const f4*)(fb + ci*16);
  #pragma unroll
  for(int k=0;k<4;k++){
    f4 v = cp[k];
    #pragma unroll
    for(int c=0;c<4;c++){ cf[4*k+c]=v[c]; nc = fmaf(v[c],v[c],nc); }
  }
  nc = sqrtf(nc);
  float acc=0.f;
  for(int k=st+lane2;k<en;k+=4){
    int m=members[k];
    const f4* mp = (const f4*)(fb + m*16);
    float dot=0.f, nm=0.f;
    #pragma unroll
    for(int kk=0;kk<4;kk++){
      f4 v = mp[kk];
      #pragma unroll
      for(int c=0;c<4;c++){ dot = fmaf(v[c], cf[4*kk+c], dot); nm = fmaf(v[c],v[c],nm); }
    }
    float sim = dot/(sqrtf(nm)*nc + EPSF);
    acc += fminf(fmaxf(sim,0.f),1.f);
  }
  acc += __shfl_xor(acc, 1, 64);
  acc += __shfl_xor(acc, 2, 64);
  if(lane2==0) ms[task] = acc / fmaxf((float)(en-st),1.f);
}

// ============ k_sim2dv: minmax + Wd + dvi ; 8 blocks x 1024 ====
__global__ __launch_bounds__(1024) void k_sim2dv(
    const float* __restrict__ ms, const float* __restrict__ W,
    const int* __restrict__ node_off, const int* __restrict__ node_edges,
    float* __restrict__ Wd, float* __restrict__ dvi)
{
  __shared__ float red1[1024], red2[1024];
  __shared__ float wdl[EE];
  int b = blockIdx.x;
  int tid = threadIdx.x;
  float msv = (tid<EE)? ms[b*EE+tid] : 0.f;
  red1[tid]=(tid<EE)? msv : 1e30f;
  red2[tid]=(tid<EE)? msv : -1e30f;
  __syncthreads();
  for(int s=512;s>0;s>>=1){
    if(tid<s){
      red1[tid]=fminf(red1[tid],red1[tid+s]);
      red2[tid]=fmaxf(red2[tid],red2[tid+s]);
    }
    __syncthreads();
  }
  if(tid<EE){
    float msn=(msv-red1[0])/(red2[0]-red1[0]+EPSF);
    float w = W[tid]*(1.f+LAMF*msn);
    Wd[b*EE+tid]=w;
    wdl[tid]=w;
  }
  __syncthreads();
  if(tid<NN){
    int st=node_off[tid], en=node_off[tid+1];
    float dv=0.f;
    for(int k=st;k<en;k++) dv += wdl[node_edges[k]];
    dvi[b*NN+tid] = rsqrtf(fmaxf(dv, EPSF));
  }
}

// ============ k_slice: per-(b,t) fused z -> v -> h2 -> conv -> hc (unchanged) ====
__global__ __launch_bounds__(1024) void k_slice(
    const float* __restrict__ x,
    const float* __restrict__ ipw, const float* __restrict__ ipb,
    const float* __restrict__ dvi, const float* __restrict__ Wd,
    const int* __restrict__ edge_nodes, const int* __restrict__ edge_cnt,
    const int* __restrict__ node_off, const int* __restrict__ node_edges,
    const float* __restrict__ cw, const float* __restrict__ cb,
    float* __restrict__ hc_out)
{
  __shared__ f4 zbuf[NN*8];         // 128000 B
  __shared__ float ipws[FIN*32];    // 2 KB
  __shared__ f4 cws4[DM*8];         // 4 KB : cw[i][4q..4q+3]
  __shared__ float wde[EE];         // 4 KB
  __shared__ int   cnts[EE];        // 4 KB
  __shared__ float ipbs[32], cbs[32];

  int tid = threadIdx.x;
  int bt  = blockIdx.x;
  int b = bt / TT, t = bt % TT;

  for(int i=tid;i<FIN*32;i+=1024) ipws[i]=ipw[i];
  for(int i=tid;i<DM*8;i+=1024) cws4[i]=((const f4*)cw)[i];
  for(int e=tid;e<EE;e+=1024){
    int c = edge_cnt[e];
    cnts[e]=c;
    wde[e]=Wd[b*EE+e]/(float)c;
  }
  if(tid<32){ ipbs[tid]=ipb[tid]; cbs[tid]=cb[tid]; }
  __syncthreads();

  const float* xb  = x + (size_t)bt*NN*FIN;
  const float* dvb = dvi + b*NN;
  float* zs = (float*)zbuf;

  // ---- Phase A: z[r,f] = dvi * (x @ ipw + ipb), swizzled write ----
  {
    int g = tid>>5, f = tid&31;
    for(int p=0;p<32;p++){
      int r = p*32+g;
      if(r<NN){
        const f4* x4 = (const f4*)(xb + r*FIN);
        float acc = ipbs[f];
        #pragma unroll
        for(int k=0;k<4;k++){
          f4 xv = x4[k];
          acc = fmaf(xv[0], ipws[(4*k+0)*32+f], acc);
          acc = fmaf(xv[1], ipws[(4*k+1)*32+f], acc);
          acc = fmaf(xv[2], ipws[(4*k+2)*32+f], acc);
          acc = fmaf(xv[3], ipws[(4*k+3)*32+f], acc);
        }
        zs[r*32 + (((f>>2)^(r&7))<<2) + (f&3)] = dvb[r]*acc;
      }
    }
  }
  __syncthreads();

  // ---- Phase B: v[e,quad] = wde * sum_{m in e} z[m,quad] ----
  int grp = tid>>3, q = tid&7;
  f4 vreg[8];
  #pragma unroll
  for(int p=0;p<8;p++){
    int e = p*128 + grp;
    f4 acc = (f4)0.f;
    if(e<EE){
      int cnt = cnts[e];
      const int* enp = edge_nodes + e*(DEG+1);
      int idx[DEG+1];
      #pragma unroll
      for(int j=0;j<DEG+1;j++) idx[j]=enp[j];
      #pragma unroll
      for(int j=0;j<DEG+1;j++){
        f4 v = zbuf[idx[j]*8 + (q ^ (idx[j]&7))];
        if(j<cnt) acc += v;
      }
      acc *= wde[e];
    }
    vreg[p]=acc;
  }
  __syncthreads();
  #pragma unroll
  for(int p=0;p<8;p++){
    int e = p*128 + grp;
    if(e<EE) zbuf[e*8 + (q^(e&7))] = vreg[p];
  }
  __syncthreads();

  // ---- Phase D: h2 gather -> conv+silu (shfl) -> hc global ----
  int lanew = tid&63, grpw = lanew>>3;
  for(int p=0;p<8;p++){
    int n = p*128 + grp;
    f4 acc = (f4)0.f;
    int st=0, en=0;
    if(n<NN){ st=node_off[n]; en=node_off[n+1]; }
    for(int j=st;j<en;j+=4){
      #pragma unroll
      for(int k=0;k<4;k++){
        int jj = (j+k<en)? j+k : st;
        int e2 = node_edges[jj];
        f4 v = zbuf[e2*8 + (q ^ (e2&7))];
        if(j+k<en) acc += v;
      }
    }
    float dvn = (n<NN)? dvb[n] : 0.f;
    acc *= dvn;          // h2 quad
    // conv 32->32 via intra-group shfl
    f4 hcq;
    #pragma unroll
    for(int c=0;c<4;c++) hcq[c]=cbs[q*4+c];
    #pragma unroll
    for(int i=0;i<32;i++){
      float h2i = __shfl(acc[i&3], grpw*8 + (i>>2), 64);
      f4 w = cws4[i*8+q];
      hcq += h2i * w;
    }
    #pragma unroll
    for(int c=0;c<4;c++) hcq[c]=siluf_(hcq[c]);
    if(n<NN) ((f4*)hc_out)[ ((size_t)(b*NN+n)*TT + t)*8 + q ] = hcq;
  }
}

// ============ k_lstm v3: chunked zx in LDS + slim recurrence ====
// block 256 = 4 waves = 8 rows. LDS 74 KB -> 2 blocks/CU.
// Phase1 (per chunk of 8 t): thread (tc,q) computes zx cols 4q..4q+3 for all 8 rows.
// Phase2: thread (r,c) serial recurrence, wh in 128 VGPRs.
__global__ __launch_bounds__(256,2) void k_lstm(const float* __restrict__ hc,
    const float* __restrict__ wh, const float* __restrict__ wx,
    const float* __restrict__ lb,
    const float* __restrict__ w1, const float* __restrict__ b1,
    const float* __restrict__ w2, const float* __restrict__ b2,
    float* __restrict__ out){
  __shared__ float hcl[8*TT*32];    // 24576 B
  __shared__ float zxl[8*8*128];    // 32768 B (one 8-t chunk)
  __shared__ f4 wxl[32*32];         // 16384 B : wx[i][4q..4q+3] at [i*32+q]
  int tid = threadIdx.x;
  int row0 = blockIdx.x*8;

  // stage hc slice (contiguous 6144 floats = 1536 f4)
  {
    const f4* hcg = (const f4*)(hc + (size_t)row0*TT*32);
    f4* hcl4 = (f4*)hcl;
    #pragma unroll
    for(int k=0;k<6;k++) hcl4[tid + k*256] = hcg[tid + k*256];
  }
  for(int i=tid;i<32*32;i+=256) wxl[i] = ((const f4*)wx)[i];

  int q = tid&31, r = tid>>5;       // phase1: (tc=r, q); phase2: (row r, chan c=q)
  int c = q;
  int base = (r&1)<<5;
  float wr0[32], wr1[32], wr2[32], wr3[32];
  #pragma unroll
  for(int i=0;i<32;i++){
    wr0[i]=wh[i*128 + c];
    wr1[i]=wh[i*128 + 32 + c];
    wr2[i]=wh[i*128 + 64 + c];
    wr3[i]=wh[i*128 + 96 + c];
  }
  f4 lbq = ((const f4*)lb)[q];
  float h=0.f, cs=0.f;
  __syncthreads();

  for(int ch=0; ch<3; ch++){
    // ---- Phase 1: zxl[rr][tc][4q..4q+3] for t = ch*8+tc, all rr ----
    {
      int t = ch*8 + r;             // this thread's t-slot
      f4 acc0=lbq, acc1=lbq, acc2=lbq, acc3=lbq, acc4=lbq, acc5=lbq, acc6=lbq, acc7=lbq;
      #pragma unroll
      for(int i=0;i<32;i++){
        f4 wv = wxl[i*32+q];
        acc0 += hcl[(0*TT+t)*32+i] * wv;
        acc1 += hcl[(1*TT+t)*32+i] * wv;
        acc2 += hcl[(2*TT+t)*32+i] * wv;
        acc3 += hcl[(3*TT+t)*32+i] * wv;
        acc4 += hcl[(4*TT+t)*32+i] * wv;
        acc5 += hcl[(5*TT+t)*32+i] * wv;
        acc6 += hcl[(6*TT+t)*32+i] * wv;
        acc7 += hcl[(7*TT+t)*32+i] * wv;
      }
      *(f4*)&zxl[(0*8+r)*128 + 4*q] = acc0;
      *(f4*)&zxl[(1*8+r)*128 + 4*q] = acc1;
      *(f4*)&zxl[(2*8+r)*128 + 4*q] = acc2;
      *(f4*)&zxl[(3*8+r)*128 + 4*q] = acc3;
      *(f4*)&zxl[(4*8+r)*128 + 4*q] = acc4;
      *(f4*)&zxl[(5*8+r)*128 + 4*q] = acc5;
      *(f4*)&zxl[(6*8+r)*128 + 4*q] = acc6;
      *(f4*)&zxl[(7*8+r)*128 + 4*q] = acc7;
    }
    __syncthreads();
    // ---- Phase 2: 8 serial steps for row r, channel c ----
    const float* zrow = &zxl[r*8*128];
    for(int tt=0;tt<8;tt++){
      float z0=zrow[tt*128+c], z1=zrow[tt*128+32+c],
            z2=zrow[tt*128+64+c], z3=zrow[tt*128+96+c];
      #pragma unroll
      for(int i=0;i<32;i++){
        float hv = __shfl(h, base+i, 64);
        z0 = fmaf(hv, wr0[i], z0);
        z1 = fmaf(hv, wr1[i], z1);
        z2 = fmaf(hv, wr2[i], z2);
        z3 = fmaf(hv, wr3[i], z3);
      }
      float ig = sigmfast_(z0);
      float fg = sigmfast_(z1);
      float gg = tanhfast_(z2);
      float og = sigmfast_(z3);
      cs = fg*cs + ig*gg;
      h = og*tanhfast_(cs);
    }
    __syncthreads();
  }

  // head
  int row = row0 + r;
  int b = row/NN, n = row%NN;
  float t1 = b1[c];
  #pragma unroll
  for(int i=0;i<32;i++){ float hv=__shfl(h, base+i, 64); t1 = fmaf(hv, w1[i*32+c], t1); }
  t1 = siluf_(t1);
  float y = (c<PREDN)? b2[c] : 0.f;
  #pragma unroll
  for(int i=0;i<32;i++){
    float tv=__shfl(t1, base+i, 64);
    if(c<PREDN) y = fmaf(tv, w2[i*PREDN+c], y);
  }
  if(c<PREDN) out[((size_t)b*PREDN + c)*NN + n] = y;
}

extern "C" void kernel_launch(void* const* d_in, const int* in_sizes, int n_in,
                              void* d_out, int out_size, void* d_ws, size_t ws_size,
                              hipStream_t stream) {
  const float* x       = (const float*)d_in[0];
  const float* xraw    = (const float*)d_in[1];
  const float* W       = (const float*)d_in[3];
  const int*   members = (const int*)d_in[4];
  const int*   centers = (const int*)d_in[5];
  const int*   offsets = (const int*)d_in[6];
  const float* ipw     = (const float*)d_in[7];
  const float* ipb     = (const float*)d_in[8];
  const float* cw      = (const float*)d_in[9];
  const float* cb      = (const float*)d_in[10];
  const float* wx      = (const float*)d_in[11];
  const float* wh      = (const float*)d_in[12];
  const float* lb      = (const float*)d_in[13];
  const float* w1      = (const float*)d_in[14];
  const float* b1      = (const float*)d_in[15];
  const float* w2      = (const float*)d_in[16];
  const float* b2      = (const float*)d_in[17];
  float* out = (float*)d_out;

  float* hc   = (float*)d_ws;                 // 6,144,000 floats
  float* feat = hc + 6144000;                 // 128,000
  float* ms   = feat + 128000;                // 8,000
  float* Wd   = ms + 8000;                    // 8,000
  float* dvi  = Wd + 8000;                    // 8,000
  int* edge_nodes = (int*)(dvi + 8000);       // 21,000
  int* edge_cnt   = edge_nodes + 21000;       // 1,000
  int* node_off   = edge_cnt + 1000;          // 1,001
  int* node_edges = node_off + 1001;          // 21,000

  k_prep<<<1, 1024, 0, stream>>>(members, centers, offsets,
                                 edge_nodes, edge_cnt, node_off, node_edges);
  k_feat<<<250, 256, 0, stream>>>(xraw, feat);
  k_sim1<<<125, 256, 0, stream>>>(feat, members, centers, offsets, ms);
  k_sim2dv<<<BB, 1024, 0, stream>>>(ms, W, node_off, node_edges, Wd, dvi);
  k_slice<<<BB*TT, 1024, 0, stream>>>(x, ipw, ipb, dvi, Wd,
                                      edge_nodes, edge_cnt, node_off, node_edges,
                                      cw, cb, hc);
  k_lstm<<<(BB*NN)/8, 256, 0, stream>>>(hc, wh, wx, lb, w1, b1, w2, b2, out);
}

// Round 8
// 306.484 us; speedup vs baseline: 2.3585x; 1.0134x over previous
//
#include <hip/hip_runtime.h>
#include <hip/hip_bf16.h>
#include <math.h>

// Problem constants (SingleHyperTKAN)
#define BB 8
#define TT 24
#define NN 1000
#define EE 1000
#define DEG 20
#define FIN 16
#define CRAW 8
#define DM 32
#define HCN 32
#define TKN 32
#define PREDN 12
#define LAMF 0.3f
#define EPSF 1e-8f

typedef float f4 __attribute__((ext_vector_type(4)));

__device__ __forceinline__ float sigmoidf_(float x){ return 1.f/(1.f+__expf(-x)); }
__device__ __forceinline__ float siluf_(float x){ return x/(1.f+__expf(-x)); }
// fast variants (v_rcp_f32, ~1 ulp)
__device__ __forceinline__ float sigmfast_(float x){
  return __builtin_amdgcn_rcpf(1.f+__expf(-x));
}
__device__ __forceinline__ float tanhfast_(float x){
  float xx = fminf(fmaxf(x,-15.f),15.f);
  float e = __expf(2.f*xx);
  return 1.f - 2.f*__builtin_amdgcn_rcpf(e+1.f);
}

// ============ k_prep: dedup edges (+0-pad) + node degree + scan + CSR ====
__global__ __launch_bounds__(1024) void k_prep(
    const int* __restrict__ members, const int* __restrict__ centers,
    const int* __restrict__ offsets,
    int* __restrict__ edge_nodes, int* __restrict__ edge_cnt,
    int* __restrict__ node_off, int* __restrict__ node_edges)
{
  __shared__ int deg[NN];
  __shared__ int cur[NN];
  __shared__ int offs[NN+1];
  __shared__ int buf[1024];
  int tid = threadIdx.x;
  for(int i=tid;i<NN;i+=1024){ deg[i]=0; cur[i]=0; }
  __syncthreads();
  int e = tid;
  int cnt = 0;
  if(e<EE){
    int st=offsets[e], en=offsets[e+1];
    int c=centers[e];
    int mem[DEG];
    #pragma unroll
    for(int k=0;k<DEG;k++) mem[k] = (st+k<en)? members[st+k] : -1;
    edge_nodes[e*(DEG+1)+0]=c;
    atomicAdd(&deg[c],1);
    cnt=1;
    #pragma unroll
    for(int k=0;k<DEG;k++){
      int m = mem[k];
      bool dup = (m==c) | (m<0);
      #pragma unroll
      for(int k2=0;k2<DEG;k2++) if(k2<k && mem[k2]==m) dup=true;
      if(!dup){
        edge_nodes[e*(DEG+1)+cnt]=m;
        atomicAdd(&deg[m],1);
        cnt++;
      }
    }
    edge_cnt[e]=cnt;
    for(int j=cnt;j<DEG+1;j++) edge_nodes[e*(DEG+1)+j]=0;   // pad: safe gather
  }
  __syncthreads();
  buf[tid] = (tid<NN)? deg[tid] : 0;
  __syncthreads();
  for(int d=1;d<1024;d<<=1){
    int v = (tid>=d)? buf[tid-d] : 0;
    __syncthreads();
    buf[tid]+=v;
    __syncthreads();
  }
  if(tid==0) offs[0]=0;
  if(tid<NN) offs[tid+1]=buf[tid];
  __syncthreads();
  if(tid<=NN) node_off[tid]=offs[tid];
  if(e<EE){
    for(int j=0;j<cnt;j++){
      int n = edge_nodes[e*(DEG+1)+j];
      int pos = atomicAdd(&cur[n],1);
      node_edges[offs[n]+pos] = e;
    }
  }
}

// ============ k_feat: mean/std over T, coalesced (n,c) ====
__global__ void k_feat(const float* __restrict__ xraw, float* __restrict__ feat){
  int tid = threadIdx.x;
  int c = tid & 7, nloc = tid >> 3;
  int row = blockIdx.x*32 + nloc;          // (b*N+n) < 8000
  if (row >= BB*NN) return;
  int b = row/NN, n = row%NN;
  float s=0.f, s2=0.f;
  for (int t=0;t<TT;t++){
    float vv = xraw[(((size_t)(b*TT+t)*NN + n)*CRAW) + c];
    s += vv; s2 += vv*vv;
  }
  float m = s*(1.f/TT);
  float var = fmaxf(s2*(1.f/TT) - m*m, 0.f);
  feat[(size_t)row*16 + c]     = m;
  feat[(size_t)row*16 + 8 + c] = sqrtf(var);
}

// ============ k_sim1: mean_sim[b,e] ; 4-lane teams, 125 blocks x 256 ====
__global__ __launch_bounds__(256) void k_sim1(
    const float* __restrict__ feat,
    const int* __restrict__ members, const int* __restrict__ centers,
    const int* __restrict__ offsets, float* __restrict__ ms)
{
  int tid = threadIdx.x;
  int lane2 = tid & 3;
  int task = blockIdx.x*64 + (tid>>2);     // (b*EE+e) < 8000
  if(task >= BB*EE) return;
  int b = task/EE, e = task%EE;
  const float* fb = feat + (size_t)b*NN*16;
  int st=offsets[e], en=offsets[e+1];
  int ci=centers[e];
  float cf[16]; float nc=0.f;
  const f4* cp = (const f4*)(fb + ci*16);
  #pragma unroll
  for(int k=0;k<4;k++){
    f4 v = cp[k];
    #pragma unroll
    for(int c=0;c<4;c++){ cf[4*k+c]=v[c]; nc = fmaf(v[c],v[c],nc); }
  }
  nc = sqrtf(nc);
  float acc=0.f;
  for(int k=st+lane2;k<en;k+=4){
    int m=members[k];
    const f4* mp = (const f4*)(fb + m*16);
    float dot=0.f, nm=0.f;
    #pragma unroll
    for(int kk=0;kk<4;kk++){
      f4 v = mp[kk];
      #pragma unroll
      for(int c=0;c<4;c++){ dot = fmaf(v[c], cf[4*kk+c], dot); nm = fmaf(v[c],v[c],nm); }
    }
    float sim = dot/(sqrtf(nm)*nc + EPSF);
    acc += fminf(fmaxf(sim,0.f),1.f);
  }
  acc += __shfl_xor(acc, 1, 64);
  acc += __shfl_xor(acc, 2, 64);
  if(lane2==0) ms[task] = acc / fmaxf((float)(en-st),1.f);
}

// ============ k_sim2dv: minmax + Wd + dvi ; 8 blocks x 1024 ====
__global__ __launch_bounds__(1024) void k_sim2dv(
    const float* __restrict__ ms, const float* __restrict__ W,
    const int* __restrict__ node_off, const int* __restrict__ node_edges,
    float* __restrict__ Wd, float* __restrict__ dvi)
{
  __shared__ float red1[1024], red2[1024];
  __shared__ float wdl[EE];
  int b = blockIdx.x;
  int tid = threadIdx.x;
  float msv = (tid<EE)? ms[b*EE+tid] : 0.f;
  red1[tid]=(tid<EE)? msv : 1e30f;
  red2[tid]=(tid<EE)? msv : -1e30f;
  __syncthreads();
  for(int s=512;s>0;s>>=1){
    if(tid<s){
      red1[tid]=fminf(red1[tid],red1[tid+s]);
      red2[tid]=fmaxf(red2[tid],red2[tid+s]);
    }
    __syncthreads();
  }
  if(tid<EE){
    float msn=(msv-red1[0])/(red2[0]-red1[0]+EPSF);
    float w = W[tid]*(1.f+LAMF*msn);
    Wd[b*EE+tid]=w;
    wdl[tid]=w;
  }
  __syncthreads();
  if(tid<NN){
    int st=node_off[tid], en=node_off[tid+1];
    float dv=0.f;
    for(int k=st;k<en;k++) dv += wdl[node_edges[k]];
    dvi[b*NN+tid] = rsqrtf(fmaxf(dv, EPSF));
  }
}

// ============ k_slice: per-(b,t) fused z -> v -> h2 -> conv -> hc ====
__global__ __launch_bounds__(1024) void k_slice(
    const float* __restrict__ x,
    const float* __restrict__ ipw, const float* __restrict__ ipb,
    const float* __restrict__ dvi, const float* __restrict__ Wd,
    const int* __restrict__ edge_nodes, const int* __restrict__ edge_cnt,
    const int* __restrict__ node_off, const int* __restrict__ node_edges,
    const float* __restrict__ cw, const float* __restrict__ cb,
    float* __restrict__ hc_out)
{
  __shared__ f4 zbuf[NN*8];         // 128000 B
  __shared__ float ipws[FIN*32];    // 2 KB
  __shared__ f4 cws4[DM*8];         // 4 KB : cw[i][4q..4q+3]
  __shared__ float wde[EE];         // 4 KB
  __shared__ int   cnts[EE];        // 4 KB
  __shared__ float ipbs[32], cbs[32];

  int tid = threadIdx.x;
  int bt  = blockIdx.x;
  int b = bt / TT, t = bt % TT;

  for(int i=tid;i<FIN*32;i+=1024) ipws[i]=ipw[i];
  for(int i=tid;i<DM*8;i+=1024) cws4[i]=((const f4*)cw)[i];
  for(int e=tid;e<EE;e+=1024){
    int c = edge_cnt[e];
    cnts[e]=c;
    wde[e]=Wd[b*EE+e]/(float)c;
  }
  if(tid<32){ ipbs[tid]=ipb[tid]; cbs[tid]=cb[tid]; }
  __syncthreads();

  const float* xb  = x + (size_t)bt*NN*FIN;
  const float* dvb = dvi + b*NN;
  float* zs = (float*)zbuf;

  // ---- Phase A: z[r,f] = dvi * (x @ ipw + ipb), swizzled write ----
  {
    int g = tid>>5, f = tid&31;
    for(int p=0;p<32;p++){
      int r = p*32+g;
      if(r<NN){
        const f4* x4 = (const f4*)(xb + r*FIN);
        float acc = ipbs[f];
        #pragma unroll
        for(int k=0;k<4;k++){
          f4 xv = x4[k];
          acc = fmaf(xv[0], ipws[(4*k+0)*32+f], acc);
          acc = fmaf(xv[1], ipws[(4*k+1)*32+f], acc);
          acc = fmaf(xv[2], ipws[(4*k+2)*32+f], acc);
          acc = fmaf(xv[3], ipws[(4*k+3)*32+f], acc);
        }
        zs[r*32 + (((f>>2)^(r&7))<<2) + (f&3)] = dvb[r]*acc;
      }
    }
  }
  __syncthreads();

  // ---- Phase B: v[e,quad] = wde * sum_{m in e} z[m,quad] ----
  int grp = tid>>3, q = tid&7;
  f4 vreg[8];
  #pragma unroll
  for(int p=0;p<8;p++){
    int e = p*128 + grp;
    f4 acc = (f4)0.f;
    if(e<EE){
      int cnt = cnts[e];
      const int* enp = edge_nodes + e*(DEG+1);
      int idx[DEG+1];
      #pragma unroll
      for(int j=0;j<DEG+1;j++) idx[j]=enp[j];
      #pragma unroll
      for(int j=0;j<DEG+1;j++){
        f4 v = zbuf[idx[j]*8 + (q ^ (idx[j]&7))];
        if(j<cnt) acc += v;
      }
      acc *= wde[e];
    }
    vreg[p]=acc;
  }
  __syncthreads();
  #pragma unroll
  for(int p=0;p<8;p++){
    int e = p*128 + grp;
    if(e<EE) zbuf[e*8 + (q^(e&7))] = vreg[p];
  }
  __syncthreads();

  // ---- Phase D: h2 gather -> conv+silu (shfl) -> hc global ----
  int lanew = tid&63, grpw = lanew>>3;
  for(int p=0;p<8;p++){
    int n = p*128 + grp;
    f4 acc = (f4)0.f;
    int st=0, en=0;
    if(n<NN){ st=node_off[n]; en=node_off[n+1]; }
    for(int j=st;j<en;j+=4){
      #pragma unroll
      for(int k=0;k<4;k++){
        int jj = (j+k<en)? j+k : st;
        int e2 = node_edges[jj];
        f4 v = zbuf[e2*8 + (q ^ (e2&7))];
        if(j+k<en) acc += v;
      }
    }
    float dvn = (n<NN)? dvb[n] : 0.f;
    acc *= dvn;          // h2 quad
    // conv 32->32 via intra-group shfl
    f4 hcq;
    #pragma unroll
    for(int c=0;c<4;c++) hcq[c]=cbs[q*4+c];
    #pragma unroll
    for(int i=0;i<32;i++){
      float h2i = __shfl(acc[i&3], grpw*8 + (i>>2), 64);
      f4 w = cws4[i*8+q];
      hcq += h2i * w;
    }
    #pragma unroll
    for(int c=0;c<4;c++) hcq[c]=siluf_(hcq[c]);
    if(n<NN) ((f4*)hc_out)[ ((size_t)(b*NN+n)*TT + t)*8 + q ] = hcq;
  }
}

// ============ k_zx: zx[item][128] = hc[item][32] @ wx + lb ; item=(row*TT+t) ====
// 3000 blocks x 256 = 64 items x 4 colgroups. wx LDS q4-interleaved (bank-safe).
__global__ __launch_bounds__(256) void k_zx(
    const float* __restrict__ hc, const float* __restrict__ wx,
    const float* __restrict__ lb, float* __restrict__ zx)
{
  __shared__ f4 wxl[32*32];   // [i][j*4+q4] = wx4[i*32 + q4*8 + j]
  __shared__ f4 lbl[32];
  int tid = threadIdx.x;
  for(int w=tid;w<1024;w+=256){
    int i = w>>5, cq = w&31;           // cq = q4*8+j
    wxl[i*32 + ((cq&7)<<2) + (cq>>3)] = ((const f4*)wx)[w];
  }
  if(tid<32) lbl[tid] = ((const f4*)lb)[tid];
  int it = tid>>2, q4 = tid&3;
  size_t item = (size_t)blockIdx.x*64 + it;   // < 192000
  const f4* hp = (const f4*)(hc + item*32);
  f4 hreg[8];
  #pragma unroll
  for(int k=0;k<8;k++) hreg[k] = hp[k];
  __syncthreads();
  f4 acc[8];
  #pragma unroll
  for(int j=0;j<8;j++) acc[j] = lbl[q4*8+j];
  #pragma unroll
  for(int i=0;i<32;i++){
    float hv = hreg[i>>2][i&3];
    #pragma unroll
    for(int j=0;j<8;j++) acc[j] += hv * wxl[i*32 + (j<<2) + q4];
  }
  f4* op = (f4*)(zx + item*128 + q4*32);
  #pragma unroll
  for(int j=0;j<8;j++) op[j] = acc[j];
}

// ============ k_lstm v4: barrier-free serial recurrence + fused head ====
// block 256 = 4 waves = 8 rows; lane c owns channel c of row r = tid>>5.
// h broadcast via tiny LDS (1 write + 8 uniform b128 reads per t; same-wave RAW).
__global__ __launch_bounds__(256,2) void k_lstm(const float* __restrict__ zx,
    const float* __restrict__ wh,
    const float* __restrict__ w1, const float* __restrict__ b1,
    const float* __restrict__ w2, const float* __restrict__ b2,
    float* __restrict__ out){
  __shared__ float hsh[8*32];
  int tid = threadIdx.x;
  int r = tid>>5, c = tid&31;
  int row = blockIdx.x*8 + r;          // < 8000
  const float* zr = zx + (size_t)row*TT*128;
  float wr0[32], wr1[32], wr2[32], wr3[32];
  #pragma unroll
  for(int i=0;i<32;i++){
    wr0[i]=wh[i*128 + c];
    wr1[i]=wh[i*128 + 32 + c];
    wr2[i]=wh[i*128 + 64 + c];
    wr3[i]=wh[i*128 + 96 + c];
  }
  const f4* hrow4 = (const f4*)&hsh[r*32];
  float h=0.f, cs=0.f;
  float p0=zr[c], p1=zr[32+c], p2=zr[64+c], p3=zr[96+c];
  for(int t=0;t<TT;t++){
    float z0=p0, z1=p1, z2=p2, z3=p3;
    if(t+1<TT){
      const float* nz = zr + (size_t)(t+1)*128;
      p0=nz[c]; p1=nz[32+c]; p2=nz[64+c]; p3=nz[96+c];
    }
    hsh[r*32+c] = h;                   // same-wave visibility (lgkmcnt)
    #pragma unroll
    for(int i4=0;i4<8;i4++){
      f4 h4 = hrow4[i4];
      #pragma unroll
      for(int k=0;k<4;k++){
        int i = i4*4+k;
        z0 = fmaf(h4[k], wr0[i], z0);
        z1 = fmaf(h4[k], wr1[i], z1);
        z2 = fmaf(h4[k], wr2[i], z2);
        z3 = fmaf(h4[k], wr3[i], z3);
      }
    }
    float ig = sigmfast_(z0);
    float fg = sigmfast_(z1);
    float gg = tanhfast_(z2);
    float og = sigmfast_(z3);
    cs = fg*cs + ig*gg;
    h = og*tanhfast_(cs);
  }
  // head: t1 = silu(h@w1+b1); y = t1@w2+b2
  int b = row/NN, n = row%NN;
  hsh[r*32+c] = h;
  float t1 = b1[c];
  #pragma unroll
  for(int i4=0;i4<8;i4++){
    f4 h4 = hrow4[i4];
    #pragma unroll
    for(int k=0;k<4;k++) t1 = fmaf(h4[k], w1[(i4*4+k)*32+c], t1);
  }
  t1 = siluf_(t1);
  hsh[r*32+c] = t1;
  float y = (c<PREDN)? b2[c] : 0.f;
  #pragma unroll
  for(int i4=0;i4<8;i4++){
    f4 t4 = hrow4[i4];
    #pragma unroll
    for(int k=0;k<4;k++){
      if(c<PREDN) y = fmaf(t4[k], w2[(i4*4+k)*PREDN+c], y);
    }
  }
  if(c<PREDN) out[((size_t)b*PREDN + c)*NN + n] = y;
}

extern "C" void kernel_launch(void* const* d_in, const int* in_sizes, int n_in,
                              void* d_out, int out_size, void* d_ws, size_t ws_size,
                              hipStream_t stream) {
  const float* x       = (const float*)d_in[0];
  const float* xraw    = (const float*)d_in[1];
  const float* W       = (const float*)d_in[3];
  const int*   members = (const int*)d_in[4];
  const int*   centers = (const int*)d_in[5];
  const int*   offsets = (const int*)d_in[6];
  const float* ipw     = (const float*)d_in[7];
  const float* ipb     = (const float*)d_in[8];
  const float* cw      = (const float*)d_in[9];
  const float* cb      = (const float*)d_in[10];
  const float* wx      = (const float*)d_in[11];
  const float* wh      = (const float*)d_in[12];
  const float* lb      = (const float*)d_in[13];
  const float* w1      = (const float*)d_in[14];
  const float* b1      = (const float*)d_in[15];
  const float* w2      = (const float*)d_in[16];
  const float* b2      = (const float*)d_in[17];
  float* out = (float*)d_out;

  float* zx   = (float*)d_ws;                 // 24,576,000 floats
  float* hc   = zx + 24576000;                // 6,144,000
  float* feat = hc + 6144000;                 // 128,000
  float* ms   = feat + 128000;                // 8,000
  float* Wd   = ms + 8000;                    // 8,000
  float* dvi  = Wd + 8000;                    // 8,000
  int* edge_nodes = (int*)(dvi + 8000);       // 21,000
  int* edge_cnt   = edge_nodes + 21000;       // 1,000
  int* node_off   = edge_cnt + 1000;          // 1,001
  int* node_edges = node_off + 1001;          // 21,000

  k_prep<<<1, 1024, 0, stream>>>(members, centers, offsets,
                                 edge_nodes, edge_cnt, node_off, node_edges);
  k_feat<<<250, 256, 0, stream>>>(xraw, feat);
  k_sim1<<<125, 256, 0, stream>>>(feat, members, centers, offsets, ms);
  k_sim2dv<<<BB, 1024, 0, stream>>>(ms, W, node_off, node_edges, Wd, dvi);
  k_slice<<<BB*TT, 1024, 0, stream>>>(x, ipw, ipb, dvi, Wd,
                                      edge_nodes, edge_cnt, node_off, node_edges,
                                      cw, cb, hc);
  k_zx<<<3000, 256, 0, stream>>>(hc, wx, lb, zx);
  k_lstm<<<(BB*NN)/8, 256, 0, stream>>>(zx, wh, w1, b1, w2, b2, out);
}

// Round 9
// 279.799 us; speedup vs baseline: 2.5834x; 1.0954x over previous
//
#include <hip/hip_runtime.h>
#include <hip/hip_bf16.h>
#include <math.h>

// Problem constants (SingleHyperTKAN)
#define BB 8
#define TT 24
#define NN 1000
#define EE 1000
#define DEG 20
#define FIN 16
#define CRAW 8
#define DM 32
#define HCN 32
#define TKN 32
#define PREDN 12
#define LAMF 0.3f
#define EPSF 1e-8f

typedef float f4 __attribute__((ext_vector_type(4)));

__device__ __forceinline__ float sigmoidf_(float x){ return 1.f/(1.f+__expf(-x)); }
__device__ __forceinline__ float siluf_(float x){ return x/(1.f+__expf(-x)); }
// fast variants (v_rcp_f32, ~1 ulp)
__device__ __forceinline__ float sigmfast_(float x){
  return __builtin_amdgcn_rcpf(1.f+__expf(-x));
}
__device__ __forceinline__ float tanhfast_(float x){
  float xx = fminf(fmaxf(x,-15.f),15.f);
  float e = __expf(2.f*xx);
  return 1.f - 2.f*__builtin_amdgcn_rcpf(e+1.f);
}

// ============ k_dedup: per-edge dedup + global node_deg atomics (wide) ====
__global__ void k_dedup(const int* __restrict__ members, const int* __restrict__ centers,
                        const int* __restrict__ offsets,
                        int* __restrict__ edge_nodes, int* __restrict__ edge_cnt,
                        int* __restrict__ node_deg){
  int e = blockIdx.x*blockDim.x + threadIdx.x;
  if(e>=EE) return;
  int st=offsets[e], en=offsets[e+1];
  int c=centers[e];
  int mem[DEG];
  #pragma unroll
  for(int k=0;k<DEG;k++) mem[k] = (st+k<en)? members[st+k] : -1;
  edge_nodes[e*(DEG+1)+0]=c;
  atomicAdd(&node_deg[c],1);
  int cnt=1;
  #pragma unroll
  for(int k=0;k<DEG;k++){
    int m = mem[k];
    bool dup = (m==c) | (m<0);
    #pragma unroll
    for(int k2=0;k2<DEG;k2++) if(k2<k && mem[k2]==m) dup=true;
    if(!dup){
      edge_nodes[e*(DEG+1)+cnt]=m;
      atomicAdd(&node_deg[m],1);
      cnt++;
    }
  }
  edge_cnt[e]=cnt;
  for(int j=cnt;j<DEG+1;j++) edge_nodes[e*(DEG+1)+j]=0;   // pad: safe gather
}

// ============ k_scan: prefix sum node_deg -> node_off (1 block) ====
__global__ __launch_bounds__(1024) void k_scan(const int* __restrict__ node_deg,
                                               int* __restrict__ node_off){
  __shared__ int buf[1024];
  int i=threadIdx.x;
  buf[i] = (i<NN)? node_deg[i]:0;
  __syncthreads();
  for(int d=1;d<1024;d<<=1){
    int v = (i>=d)? buf[i-d] : 0;
    __syncthreads();
    buf[i]+=v;
    __syncthreads();
  }
  if(i==0) node_off[0]=0;
  if(i<NN) node_off[i+1]=buf[i];
}

// ============ k_fill: node->edge CSR via atomic cursor (wide) ====
__global__ void k_fill(const int* __restrict__ edge_nodes, const int* __restrict__ edge_cnt,
                       const int* __restrict__ node_off, int* __restrict__ cursor,
                       int* __restrict__ node_edges){
  int e = blockIdx.x*blockDim.x + threadIdx.x;
  if(e>=EE) return;
  int cnt=edge_cnt[e];
  for(int j=0;j<cnt;j++){
    int n = edge_nodes[e*(DEG+1)+j];
    int pos = atomicAdd(&cursor[n],1);
    node_edges[node_off[n]+pos] = e;
  }
}

// ============ k_feat: mean/std over T, coalesced (n,c) ====
__global__ void k_feat(const float* __restrict__ xraw, float* __restrict__ feat){
  int tid = threadIdx.x;
  int c = tid & 7, nloc = tid >> 3;
  int row = blockIdx.x*32 + nloc;          // (b*N+n) < 8000
  if (row >= BB*NN) return;
  int b = row/NN, n = row%NN;
  float s=0.f, s2=0.f;
  for (int t=0;t<TT;t++){
    float vv = xraw[(((size_t)(b*TT+t)*NN + n)*CRAW) + c];
    s += vv; s2 += vv*vv;
  }
  float m = s*(1.f/TT);
  float var = fmaxf(s2*(1.f/TT) - m*m, 0.f);
  feat[(size_t)row*16 + c]     = m;
  feat[(size_t)row*16 + 8 + c] = sqrtf(var);
}

// ============ k_sim1: mean_sim[b,e] ; 4-lane teams, 125 blocks x 256 ====
__global__ __launch_bounds__(256) void k_sim1(
    const float* __restrict__ feat,
    const int* __restrict__ members, const int* __restrict__ centers,
    const int* __restrict__ offsets, float* __restrict__ ms)
{
  int tid = threadIdx.x;
  int lane2 = tid & 3;
  int task = blockIdx.x*64 + (tid>>2);     // (b*EE+e) < 8000
  if(task >= BB*EE) return;
  int b = task/EE, e = task%EE;
  const float* fb = feat + (size_t)b*NN*16;
  int st=offsets[e], en=offsets[e+1];
  int ci=centers[e];
  float cf[16]; float nc=0.f;
  const f4* cp = (const f4*)(fb + ci*16);
  #pragma unroll
  for(int k=0;k<4;k++){
    f4 v = cp[k];
    #pragma unroll
    for(int c=0;c<4;c++){ cf[4*k+c]=v[c]; nc = fmaf(v[c],v[c],nc); }
  }
  nc = sqrtf(nc);
  float acc=0.f;
  for(int k=st+lane2;k<en;k+=4){
    int m=members[k];
    const f4* mp = (const f4*)(fb + m*16);
    float dot=0.f, nm=0.f;
    #pragma unroll
    for(int kk=0;kk<4;kk++){
      f4 v = mp[kk];
      #pragma unroll
      for(int c=0;c<4;c++){ dot = fmaf(v[c], cf[4*kk+c], dot); nm = fmaf(v[c],v[c],nm); }
    }
    float sim = dot/(sqrtf(nm)*nc + EPSF);
    acc += fminf(fmaxf(sim,0.f),1.f);
  }
  acc += __shfl_xor(acc, 1, 64);
  acc += __shfl_xor(acc, 2, 64);
  if(lane2==0) ms[task] = acc / fmaxf((float)(en-st),1.f);
}

// ============ k_sim2dv: minmax + Wd + dvi ; 8 blocks x 1024 ====
__global__ __launch_bounds__(1024) void k_sim2dv(
    const float* __restrict__ ms, const float* __restrict__ W,
    const int* __restrict__ node_off, const int* __restrict__ node_edges,
    float* __restrict__ Wd, float* __restrict__ dvi)
{
  __shared__ float red1[1024], red2[1024];
  __shared__ float wdl[EE];
  int b = blockIdx.x;
  int tid = threadIdx.x;
  float msv = (tid<EE)? ms[b*EE+tid] : 0.f;
  red1[tid]=(tid<EE)? msv : 1e30f;
  red2[tid]=(tid<EE)? msv : -1e30f;
  __syncthreads();
  for(int s=512;s>0;s>>=1){
    if(tid<s){
      red1[tid]=fminf(red1[tid],red1[tid+s]);
      red2[tid]=fmaxf(red2[tid],red2[tid+s]);
    }
    __syncthreads();
  }
  if(tid<EE){
    float msn=(msv-red1[0])/(red2[0]-red1[0]+EPSF);
    float w = W[tid]*(1.f+LAMF*msn);
    Wd[b*EE+tid]=w;
    wdl[tid]=w;
  }
  __syncthreads();
  if(tid<NN){
    int st=node_off[tid], en=node_off[tid+1];
    float dv=0.f;
    for(int k=st;k<en;k++) dv += wdl[node_edges[k]];
    dvi[b*NN+tid] = rsqrtf(fmaxf(dv, EPSF));
  }
}

// ============ k_slice: per-(b,t) fused z -> v -> h2 -> conv -> hc ====
__global__ __launch_bounds__(1024) void k_slice(
    const float* __restrict__ x,
    const float* __restrict__ ipw, const float* __restrict__ ipb,
    const float* __restrict__ dvi, const float* __restrict__ Wd,
    const int* __restrict__ edge_nodes, const int* __restrict__ edge_cnt,
    const int* __restrict__ node_off, const int* __restrict__ node_edges,
    const float* __restrict__ cw, const float* __restrict__ cb,
    float* __restrict__ hc_out)
{
  __shared__ f4 zbuf[NN*8];         // 128000 B
  __shared__ float ipws[FIN*32];    // 2 KB
  __shared__ f4 cws4[DM*8];         // 4 KB : cw[i][4q..4q+3]
  __shared__ float wde[EE];         // 4 KB
  __shared__ int   cnts[EE];        // 4 KB
  __shared__ float ipbs[32], cbs[32];

  int tid = threadIdx.x;
  int bt  = blockIdx.x;
  int b = bt / TT, t = bt % TT;

  for(int i=tid;i<FIN*32;i+=1024) ipws[i]=ipw[i];
  for(int i=tid;i<DM*8;i+=1024) cws4[i]=((const f4*)cw)[i];
  for(int e=tid;e<EE;e+=1024){
    int c = edge_cnt[e];
    cnts[e]=c;
    wde[e]=Wd[b*EE+e]/(float)c;
  }
  if(tid<32){ ipbs[tid]=ipb[tid]; cbs[tid]=cb[tid]; }
  __syncthreads();

  const float* xb  = x + (size_t)bt*NN*FIN;
  const float* dvb = dvi + b*NN;
  float* zs = (float*)zbuf;

  // ---- Phase A: z[r,f] = dvi * (x @ ipw + ipb), swizzled write ----
  {
    int g = tid>>5, f = tid&31;
    for(int p=0;p<32;p++){
      int r = p*32+g;
      if(r<NN){
        const f4* x4 = (const f4*)(xb + r*FIN);
        float acc = ipbs[f];
        #pragma unroll
        for(int k=0;k<4;k++){
          f4 xv = x4[k];
          acc = fmaf(xv[0], ipws[(4*k+0)*32+f], acc);
          acc = fmaf(xv[1], ipws[(4*k+1)*32+f], acc);
          acc = fmaf(xv[2], ipws[(4*k+2)*32+f], acc);
          acc = fmaf(xv[3], ipws[(4*k+3)*32+f], acc);
        }
        zs[r*32 + (((f>>2)^(r&7))<<2) + (f&3)] = dvb[r]*acc;
      }
    }
  }
  __syncthreads();

  // ---- Phase B: v[e,quad] = wde * sum_{m in e} z[m,quad] ----
  int grp = tid>>3, q = tid&7;
  f4 vreg[8];
  #pragma unroll
  for(int p=0;p<8;p++){
    int e = p*128 + grp;
    f4 acc = (f4)0.f;
    if(e<EE){
      int cnt = cnts[e];
      const int* enp = edge_nodes + e*(DEG+1);
      int idx[DEG+1];
      #pragma unroll
      for(int j=0;j<DEG+1;j++) idx[j]=enp[j];
      #pragma unroll
      for(int j=0;j<DEG+1;j++){
        f4 v = zbuf[idx[j]*8 + (q ^ (idx[j]&7))];
        if(j<cnt) acc += v;
      }
      acc *= wde[e];
    }
    vreg[p]=acc;
  }
  __syncthreads();
  #pragma unroll
  for(int p=0;p<8;p++){
    int e = p*128 + grp;
    if(e<EE) zbuf[e*8 + (q^(e&7))] = vreg[p];
  }
  __syncthreads();

  // ---- Phase D: h2 gather (prefetched indices) -> conv+silu -> hc ----
  int lanew = tid&63, grpw = lanew>>3;
  for(int p=0;p<8;p++){
    int n = p*128 + grp;
    int st=0, deg=0;
    if(n<NN){ st=node_off[n]; deg=node_off[n+1]-st; }
    // up-front independent loads (one latency for all)
    int idx[24];
    #pragma unroll
    for(int k=0;k<24;k++) idx[k] = (k<deg)? node_edges[st+k] : 0;
    f4 acc = (f4)0.f;
    #pragma unroll
    for(int k=0;k<24;k++){
      int e2 = idx[k];
      f4 v = zbuf[e2*8 + (q ^ (e2&7))];
      if(k<deg) acc += v;
    }
    for(int j=st+24;j<st+deg;j++){      // rare tail (deg>24)
      int e2 = node_edges[j];
      acc += zbuf[e2*8 + (q ^ (e2&7))];
    }
    float dvn = (n<NN)? dvb[n] : 0.f;
    acc *= dvn;          // h2 quad
    // conv 32->32 via intra-group shfl
    f4 hcq;
    #pragma unroll
    for(int c=0;c<4;c++) hcq[c]=cbs[q*4+c];
    #pragma unroll
    for(int i=0;i<32;i++){
      float h2i = __shfl(acc[i&3], grpw*8 + (i>>2), 64);
      f4 w = cws4[i*8+q];
      hcq += h2i * w;
    }
    #pragma unroll
    for(int c=0;c<4;c++) hcq[c]=siluf_(hcq[c]);
    if(n<NN) ((f4*)hc_out)[ ((size_t)(b*NN+n)*TT + t)*8 + q ] = hcq;
  }
}

// ============ k_zx v2: zx = hc @ wx + lb, register-blocked ====
// 3000 blocks x 256 = 64 items; thread (ig=tid>>5, q4=tid&31): 8 items x 1 col-quad.
// Per 4-i chunk: 4 wx b128 + 8 hc b128 -> 128 FMA (VALU-bound).
__global__ __launch_bounds__(256) void k_zx(
    const float* __restrict__ hc, const float* __restrict__ wx,
    const float* __restrict__ lb, float* __restrict__ zx)
{
  __shared__ f4 wxl[32*32];   // [i][q] at i*32+q
  __shared__ f4 hcl[64*8];    // 64 items x 8 f4
  __shared__ f4 lbl[32];
  int tid = threadIdx.x;
  for(int w=tid;w<1024;w+=256) wxl[w] = ((const f4*)wx)[w];
  if(tid<32) lbl[tid] = ((const f4*)lb)[tid];
  size_t base = (size_t)blockIdx.x*64;
  {
    const f4* hp = (const f4*)(hc + base*32);
    hcl[tid]     = hp[tid];
    hcl[tid+256] = hp[tid+256];
  }
  __syncthreads();
  int ig = tid>>5, q4 = tid&31;
  f4 acc[8];
  f4 l = lbl[q4];
  #pragma unroll
  for(int it=0;it<8;it++) acc[it]=l;
  #pragma unroll
  for(int c=0;c<8;c++){
    f4 w0 = wxl[(4*c+0)*32+q4];
    f4 w1 = wxl[(4*c+1)*32+q4];
    f4 w2 = wxl[(4*c+2)*32+q4];
    f4 w3 = wxl[(4*c+3)*32+q4];
    #pragma unroll
    for(int it=0;it<8;it++){
      f4 h4 = hcl[(ig*8+it)*8 + c];
      acc[it] += h4[0]*w0;
      acc[it] += h4[1]*w1;
      acc[it] += h4[2]*w2;
      acc[it] += h4[3]*w3;
    }
  }
  #pragma unroll
  for(int it=0;it<8;it++){
    ((f4*)(zx + (base + (size_t)(ig*8+it))*128))[q4] = acc[it];
  }
}

// ============ k_lstm v4: barrier-free serial recurrence + fused head ====
// block 256 = 4 waves = 8 rows; lane c owns channel c of row r = tid>>5.
// h broadcast via tiny LDS (1 write + 8 uniform b128 reads per t; same-wave RAW).
__global__ __launch_bounds__(256,2) void k_lstm(const float* __restrict__ zx,
    const float* __restrict__ wh,
    const float* __restrict__ w1, const float* __restrict__ b1,
    const float* __restrict__ w2, const float* __restrict__ b2,
    float* __restrict__ out){
  __shared__ float hsh[8*32];
  int tid = threadIdx.x;
  int r = tid>>5, c = tid&31;
  int row = blockIdx.x*8 + r;          // < 8000
  const float* zr = zx + (size_t)row*TT*128;
  float wr0[32], wr1[32], wr2[32], wr3[32];
  #pragma unroll
  for(int i=0;i<32;i++){
    wr0[i]=wh[i*128 + c];
    wr1[i]=wh[i*128 + 32 + c];
    wr2[i]=wh[i*128 + 64 + c];
    wr3[i]=wh[i*128 + 96 + c];
  }
  const f4* hrow4 = (const f4*)&hsh[r*32];
  float h=0.f, cs=0.f;
  float p0=zr[c], p1=zr[32+c], p2=zr[64+c], p3=zr[96+c];
  for(int t=0;t<TT;t++){
    float z0=p0, z1=p1, z2=p2, z3=p3;
    if(t+1<TT){
      const float* nz = zr + (size_t)(t+1)*128;
      p0=nz[c]; p1=nz[32+c]; p2=nz[64+c]; p3=nz[96+c];
    }
    hsh[r*32+c] = h;                   // same-wave visibility (lgkmcnt)
    #pragma unroll
    for(int i4=0;i4<8;i4++){
      f4 h4 = hrow4[i4];
      #pragma unroll
      for(int k=0;k<4;k++){
        int i = i4*4+k;
        z0 = fmaf(h4[k], wr0[i], z0);
        z1 = fmaf(h4[k], wr1[i], z1);
        z2 = fmaf(h4[k], wr2[i], z2);
        z3 = fmaf(h4[k], wr3[i], z3);
      }
    }
    float ig = sigmfast_(z0);
    float fg = sigmfast_(z1);
    float gg = tanhfast_(z2);
    float og = sigmfast_(z3);
    cs = fg*cs + ig*gg;
    h = og*tanhfast_(cs);
  }
  // head: t1 = silu(h@w1+b1); y = t1@w2+b2
  int b = row/NN, n = row%NN;
  hsh[r*32+c] = h;
  float t1 = b1[c];
  #pragma unroll
  for(int i4=0;i4<8;i4++){
    f4 h4 = hrow4[i4];
    #pragma unroll
    for(int k=0;k<4;k++) t1 = fmaf(h4[k], w1[(i4*4+k)*32+c], t1);
  }
  t1 = siluf_(t1);
  hsh[r*32+c] = t1;
  float y = (c<PREDN)? b2[c] : 0.f;
  #pragma unroll
  for(int i4=0;i4<8;i4++){
    f4 t4 = hrow4[i4];
    #pragma unroll
    for(int k=0;k<4;k++){
      if(c<PREDN) y = fmaf(t4[k], w2[(i4*4+k)*PREDN+c], y);
    }
  }
  if(c<PREDN) out[((size_t)b*PREDN + c)*NN + n] = y;
}

extern "C" void kernel_launch(void* const* d_in, const int* in_sizes, int n_in,
                              void* d_out, int out_size, void* d_ws, size_t ws_size,
                              hipStream_t stream) {
  const float* x       = (const float*)d_in[0];
  const float* xraw    = (const float*)d_in[1];
  const float* W       = (const float*)d_in[3];
  const int*   members = (const int*)d_in[4];
  const int*   centers = (const int*)d_in[5];
  const int*   offsets = (const int*)d_in[6];
  const float* ipw     = (const float*)d_in[7];
  const float* ipb     = (const float*)d_in[8];
  const float* cw      = (const float*)d_in[9];
  const float* cb      = (const float*)d_in[10];
  const float* wx      = (const float*)d_in[11];
  const float* wh      = (const float*)d_in[12];
  const float* lb      = (const float*)d_in[13];
  const float* w1      = (const float*)d_in[14];
  const float* b1      = (const float*)d_in[15];
  const float* w2      = (const float*)d_in[16];
  const float* b2      = (const float*)d_in[17];
  float* out = (float*)d_out;

  float* zx   = (float*)d_ws;                 // 24,576,000 floats
  float* hc   = zx + 24576000;                // 6,144,000
  float* feat = hc + 6144000;                 // 128,000
  float* ms   = feat + 128000;                // 8,000
  float* Wd   = ms + 8000;                    // 8,000
  float* dvi  = Wd + 8000;                    // 8,000
  int* edge_nodes = (int*)(dvi + 8000);       // 21,000
  int* edge_cnt   = edge_nodes + 21000;       // 1,000
  int* node_off   = edge_cnt + 1000;          // 1,001
  int* node_deg   = node_off + 1001;          // 1,000
  int* cursor     = node_deg + 1000;          // 1,000
  int* node_edges = cursor + 1000;            // 21,000

  hipMemsetAsync(node_deg, 0, 2000*sizeof(int), stream);   // node_deg + cursor

  k_feat<<<250, 256, 0, stream>>>(xraw, feat);
  k_dedup<<<(EE+255)/256, 256, 0, stream>>>(members, centers, offsets,
                                            edge_nodes, edge_cnt, node_deg);
  k_scan<<<1, 1024, 0, stream>>>(node_deg, node_off);
  k_fill<<<(EE+255)/256, 256, 0, stream>>>(edge_nodes, edge_cnt, node_off,
                                           cursor, node_edges);
  k_sim1<<<125, 256, 0, stream>>>(feat, members, centers, offsets, ms);
  k_sim2dv<<<BB, 1024, 0, stream>>>(ms, W, node_off, node_edges, Wd, dvi);
  k_slice<<<BB*TT, 1024, 0, stream>>>(x, ipw, ipb, dvi, Wd,
                                      edge_nodes, edge_cnt, node_off, node_edges,
                                      cw, cb, hc);
  k_zx<<<3000, 256, 0, stream>>>(hc, wx, lb, zx);
  k_lstm<<<(BB*NN)/8, 256, 0, stream>>>(zx, wh, w1, b1, w2, b2, out);
}

// Round 11
// 273.159 us; speedup vs baseline: 2.6462x; 1.0243x over previous
//
#include <hip/hip_runtime.h>
#include <hip/hip_bf16.h>
#include <math.h>

// Problem constants (SingleHyperTKAN)
#define BB 8
#define TT 24
#define NN 1000
#define EE 1000
#define DEG 20
#define FIN 16
#define CRAW 8
#define DM 32
#define HCN 32
#define TKN 32
#define PREDN 12
#define LAMF 0.3f
#define EPSF 1e-8f

typedef float f4 __attribute__((ext_vector_type(4)));

__device__ __forceinline__ float sigmoidf_(float x){ return 1.f/(1.f+__expf(-x)); }
__device__ __forceinline__ float siluf_(float x){ return x/(1.f+__expf(-x)); }
// fast variants (v_rcp_f32, ~1 ulp)
__device__ __forceinline__ float sigmfast_(float x){
  return __builtin_amdgcn_rcpf(1.f+__expf(-x));
}
__device__ __forceinline__ float tanhfast_(float x){
  float xx = fminf(fmaxf(x,-15.f),15.f);
  float e = __expf(2.f*xx);
  return 1.f - 2.f*__builtin_amdgcn_rcpf(e+1.f);
}

// ============ k_dedup: per-edge dedup + global node_deg atomics (wide) ====
__global__ void k_dedup(const int* __restrict__ members, const int* __restrict__ centers,
                        const int* __restrict__ offsets,
                        int* __restrict__ edge_nodes, int* __restrict__ edge_cnt,
                        int* __restrict__ node_deg){
  int e = blockIdx.x*blockDim.x + threadIdx.x;
  if(e>=EE) return;
  int st=offsets[e], en=offsets[e+1];
  int c=centers[e];
  int mem[DEG];
  #pragma unroll
  for(int k=0;k<DEG;k++) mem[k] = (st+k<en)? members[st+k] : -1;
  edge_nodes[e*(DEG+1)+0]=c;
  atomicAdd(&node_deg[c],1);
  int cnt=1;
  #pragma unroll
  for(int k=0;k<DEG;k++){
    int m = mem[k];
    bool dup = (m==c) | (m<0);
    #pragma unroll
    for(int k2=0;k2<DEG;k2++) if(k2<k && mem[k2]==m) dup=true;
    if(!dup){
      edge_nodes[e*(DEG+1)+cnt]=m;
      atomicAdd(&node_deg[m],1);
      cnt++;
    }
  }
  edge_cnt[e]=cnt;
  for(int j=cnt;j<DEG+1;j++) edge_nodes[e*(DEG+1)+j]=0;   // pad: safe gather
}

// ============ k_scan: prefix sum node_deg -> node_off (1 block) ====
__global__ __launch_bounds__(1024) void k_scan(const int* __restrict__ node_deg,
                                               int* __restrict__ node_off){
  __shared__ int buf[1024];
  int i=threadIdx.x;
  buf[i] = (i<NN)? node_deg[i]:0;
  __syncthreads();
  for(int d=1;d<1024;d<<=1){
    int v = (i>=d)? buf[i-d] : 0;
    __syncthreads();
    buf[i]+=v;
    __syncthreads();
  }
  if(i==0) node_off[0]=0;
  if(i<NN) node_off[i+1]=buf[i];
}

// ============ k_fill: node->edge CSR via atomic cursor (wide) ====
__global__ void k_fill(const int* __restrict__ edge_nodes, const int* __restrict__ edge_cnt,
                       const int* __restrict__ node_off, int* __restrict__ cursor,
                       int* __restrict__ node_edges){
  int e = blockIdx.x*blockDim.x + threadIdx.x;
  if(e>=EE) return;
  int cnt=edge_cnt[e];
  for(int j=0;j<cnt;j++){
    int n = edge_nodes[e*(DEG+1)+j];
    int pos = atomicAdd(&cursor[n],1);
    node_edges[node_off[n]+pos] = e;
  }
}

// ============ k_feat: mean/std over T, coalesced (n,c) ====
__global__ void k_feat(const float* __restrict__ xraw, float* __restrict__ feat){
  int tid = threadIdx.x;
  int c = tid & 7, nloc = tid >> 3;
  int row = blockIdx.x*32 + nloc;          // (b*N+n) < 8000
  if (row >= BB*NN) return;
  int b = row/NN, n = row%NN;
  float s=0.f, s2=0.f;
  for (int t=0;t<TT;t++){
    float vv = xraw[(((size_t)(b*TT+t)*NN + n)*CRAW) + c];
    s += vv; s2 += vv*vv;
  }
  float m = s*(1.f/TT);
  float var = fmaxf(s2*(1.f/TT) - m*m, 0.f);
  feat[(size_t)row*16 + c]     = m;
  feat[(size_t)row*16 + 8 + c] = sqrtf(var);
}

// ============ k_sim1: mean_sim[b,e] ; 4-lane teams, 125 blocks x 256 ====
__global__ __launch_bounds__(256) void k_sim1(
    const float* __restrict__ feat,
    const int* __restrict__ members, const int* __restrict__ centers,
    const int* __restrict__ offsets, float* __restrict__ ms)
{
  int tid = threadIdx.x;
  int lane2 = tid & 3;
  int task = blockIdx.x*64 + (tid>>2);     // (b*EE+e) < 8000
  if(task >= BB*EE) return;
  int b = task/EE, e = task%EE;
  const float* fb = feat + (size_t)b*NN*16;
  int st=offsets[e], en=offsets[e+1];
  int ci=centers[e];
  float cf[16]; float nc=0.f;
  const f4* cp = (const f4*)(fb + ci*16);
  #pragma unroll
  for(int k=0;k<4;k++){
    f4 v = cp[k];
    #pragma unroll
    for(int c=0;c<4;c++){ cf[4*k+c]=v[c]; nc = fmaf(v[c],v[c],nc); }
  }
  nc = sqrtf(nc);
  float acc=0.f;
  for(int k=st+lane2;k<en;k+=4){
    int m=members[k];
    const f4* mp = (const f4*)(fb + m*16);
    float dot=0.f, nm=0.f;
    #pragma unroll
    for(int kk=0;kk<4;kk++){
      f4 v = mp[kk];
      #pragma unroll
      for(int c=0;c<4;c++){ dot = fmaf(v[c], cf[4*kk+c], dot); nm = fmaf(v[c],v[c],nm); }
    }
    float sim = dot/(sqrtf(nm)*nc + EPSF);
    acc += fminf(fmaxf(sim,0.f),1.f);
  }
  acc += __shfl_xor(acc, 1, 64);
  acc += __shfl_xor(acc, 2, 64);
  if(lane2==0) ms[task] = acc / fmaxf((float)(en-st),1.f);
}

// ============ k_sim2dv: minmax + Wd + dvi ; 8 blocks x 1024 ====
__global__ __launch_bounds__(1024) void k_sim2dv(
    const float* __restrict__ ms, const float* __restrict__ W,
    const int* __restrict__ node_off, const int* __restrict__ node_edges,
    float* __restrict__ Wd, float* __restrict__ dvi)
{
  __shared__ float red1[1024], red2[1024];
  __shared__ float wdl[EE];
  int b = blockIdx.x;
  int tid = threadIdx.x;
  float msv = (tid<EE)? ms[b*EE+tid] : 0.f;
  red1[tid]=(tid<EE)? msv : 1e30f;
  red2[tid]=(tid<EE)? msv : -1e30f;
  __syncthreads();
  for(int s=512;s>0;s>>=1){
    if(tid<s){
      red1[tid]=fminf(red1[tid],red1[tid+s]);
      red2[tid]=fmaxf(red2[tid],red2[tid+s]);
    }
    __syncthreads();
  }
  if(tid<EE){
    float msn=(msv-red1[0])/(red2[0]-red1[0]+EPSF);
    float w = W[tid]*(1.f+LAMF*msn);
    Wd[b*EE+tid]=w;
    wdl[tid]=w;
  }
  __syncthreads();
  if(tid<NN){
    int st=node_off[tid], en=node_off[tid+1];
    float dv=0.f;
    for(int k=st;k<en;k++) dv += wdl[node_edges[k]];
    dvi[b*NN+tid] = rsqrtf(fmaxf(dv, EPSF));
  }
}

// ============ k_slice v4: channel-split fused z -> v -> h2 ====
// grid 384 = 192 slices x 2 halves; block 1024; LDS ~74 KB -> 2 blocks/CU.
// zbuf[n][4] f4 (16 channels), swizzle quad: q ^= (n>>1)&3.
// h2g written in (b, n, t) item order to match k_zx/k_lstm consumption!
__global__ __launch_bounds__(1024,2) void k_slice(
    const float* __restrict__ x,
    const float* __restrict__ ipw, const float* __restrict__ ipb,
    const float* __restrict__ dvi, const float* __restrict__ Wd,
    const int* __restrict__ edge_nodes, const int* __restrict__ edge_cnt,
    const int* __restrict__ node_off, const int* __restrict__ node_edges,
    float* __restrict__ h2g)
{
  __shared__ f4 zbuf[NN*4];         // 64000 B
  __shared__ float wde[EE];         // 4 KB
  __shared__ int   cnts[EE];        // 4 KB
  __shared__ float ipws[FIN*16];    // 1 KB (this half's columns)
  __shared__ float ipbs[16];

  int tid = threadIdx.x;
  int blk = blockIdx.x;
  int bt = blk >> 1, half = blk & 1;
  int b = bt / TT, t = bt % TT;
  int coff = half << 4;

  for(int i=tid;i<FIN*16;i+=1024){ int row=i>>4, c=i&15; ipws[i]=ipw[row*32 + coff + c]; }
  if(tid<16) ipbs[tid]=ipb[coff+tid];
  for(int e=tid;e<EE;e+=1024){
    int c = edge_cnt[e];
    cnts[e]=c;
    wde[e]=Wd[b*EE+e]/(float)c;
  }
  __syncthreads();

  const float* xb  = x + (size_t)bt*NN*FIN;
  const float* dvb = dvi + b*NN;
  float* zs = (float*)zbuf;

  // ---- Phase A: z[r, coff+f] (swizzled write) ----
  {
    int g = tid>>4, f = tid&15;
    int q = f>>2, l = f&3;
    for(int p=0;p<16;p++){
      int r = p*64+g;
      if(r<NN){
        const f4* x4 = (const f4*)(xb + (size_t)r*FIN);
        float acc = ipbs[f];
        #pragma unroll
        for(int k=0;k<4;k++){
          f4 xv = x4[k];
          acc = fmaf(xv[0], ipws[(4*k+0)*16+f], acc);
          acc = fmaf(xv[1], ipws[(4*k+1)*16+f], acc);
          acc = fmaf(xv[2], ipws[(4*k+2)*16+f], acc);
          acc = fmaf(xv[3], ipws[(4*k+3)*16+f], acc);
        }
        zs[r*16 + ((q ^ ((r>>1)&3))<<2) + l] = dvb[r]*acc;
      }
    }
  }
  __syncthreads();

  // ---- Phase B: v[e,q] = wde * sum_{m in e} z[m,q] ----
  int grp = tid>>2, q = tid&3;
  f4 vreg[4];
  #pragma unroll
  for(int p=0;p<4;p++){
    int e = p*256 + grp;
    f4 acc = (f4)0.f;
    if(e<EE){
      int cnt = cnts[e];
      const int* enp = edge_nodes + e*(DEG+1);
      for(int j0=0;j0<DEG+1;j0+=8){
        int idx[8];
        #pragma unroll
        for(int k=0;k<8;k++) idx[k] = (j0+k<DEG+1)? enp[j0+k] : 0;
        #pragma unroll
        for(int k=0;k<8;k++){
          int m = idx[k];
          f4 v = zbuf[m*4 + (q ^ ((m>>1)&3))];
          if(j0+k<cnt) acc += v;
        }
      }
      acc *= wde[e];
    }
    vreg[p]=acc;
  }
  __syncthreads();
  #pragma unroll
  for(int p=0;p<4;p++){
    int e = p*256 + grp;
    if(e<EE) zbuf[e*4 + (q^((e>>1)&3))] = vreg[p];
  }
  __syncthreads();

  // ---- Phase D: h2[n,q] = dvi * sum_{e ∋ n} v[e,q] -> global (b,n,t layout) ----
  #pragma unroll
  for(int p=0;p<4;p++){
    int n = p*256 + grp;
    if(n<NN){
      int st=node_off[n], deg=node_off[n+1]-st;
      f4 acc = (f4)0.f;
      for(int j0=0;j0<deg;j0+=8){
        int idx[8];
        int m8 = deg - j0;
        #pragma unroll
        for(int k=0;k<8;k++) idx[k] = (k<m8)? node_edges[st+j0+k] : 0;
        #pragma unroll
        for(int k=0;k<8;k++){
          int e2 = idx[k];
          f4 v = zbuf[e2*4 + (q ^ ((e2>>1)&3))];
          if(k<m8) acc += v;
        }
      }
      acc *= dvb[n];
      // (b, n, t) item order: item = (b*NN+n)*TT + t
      ((f4*)(h2g + (((size_t)(b*NN+n))*TT + t)*32 + coff))[q] = acc;
    }
  }
}

// ============ k_zx v3: hc = silu(h2@cw+cb); zx = hc@wx+lb ====
// 3000 blocks x 256 = 64 items (item=(b*NN+n)*TT+t, linear). conv -> LDS -> proj.
__global__ __launch_bounds__(256) void k_zx(
    const float* __restrict__ h2, const float* __restrict__ cw,
    const float* __restrict__ cb,
    const float* __restrict__ wx, const float* __restrict__ lb,
    float* __restrict__ zx)
{
  __shared__ f4 wxl[32*32];     // 16 KB
  __shared__ f4 cwl[32*8];      // 4 KB
  __shared__ float hl[64*36];   // 9.2 KB, pad 36 (bank-spread row reads)
  __shared__ f4 hcl[64*8];      // 8 KB
  __shared__ f4 lbl[32];
  __shared__ f4 cbl[8];
  int tid = threadIdx.x;
  for(int w=tid;w<1024;w+=256) wxl[w] = ((const f4*)wx)[w];
  if(tid<256) cwl[tid] = ((const f4*)cw)[tid];
  if(tid<32) lbl[tid] = ((const f4*)lb)[tid];
  if(tid<8)  cbl[tid] = ((const f4*)cb)[tid];
  size_t base = (size_t)blockIdx.x*64;
  {
    const f4* hp = (const f4*)(h2 + base*32);
    #pragma unroll
    for(int rep=0;rep<2;rep++){
      int w = tid + rep*256;            // f4 index < 512
      int it = w>>3, qc = w&7;
      *(f4*)&hl[it*36 + qc*4] = hp[w];
    }
  }
  __syncthreads();
  // conv+silu: 512 tasks = 64 items x 8 chan-quads
  #pragma unroll
  for(int rep=0;rep<2;rep++){
    int task = tid + rep*256;
    int it = task>>3, qc = task&7;
    const float* hrow = &hl[it*36];
    f4 a = cbl[qc];
    #pragma unroll
    for(int i=0;i<32;i++) a += hrow[i]*cwl[i*8+qc];
    #pragma unroll
    for(int c=0;c<4;c++) a[c]=siluf_(a[c]);
    hcl[it*8+qc]=a;
  }
  __syncthreads();
  // proj: thread (ig=tid>>5, q4=tid&31): 8 items x 1 col-quad
  int ig = tid>>5, q4 = tid&31;
  f4 acc[8];
  f4 l = lbl[q4];
  #pragma unroll
  for(int it=0;it<8;it++) acc[it]=l;
  #pragma unroll
  for(int c=0;c<8;c++){
    f4 w0 = wxl[(4*c+0)*32+q4];
    f4 w1 = wxl[(4*c+1)*32+q4];
    f4 w2 = wxl[(4*c+2)*32+q4];
    f4 w3 = wxl[(4*c+3)*32+q4];
    #pragma unroll
    for(int it=0;it<8;it++){
      f4 h4 = hcl[(ig*8+it)*8 + c];
      acc[it] += h4[0]*w0;
      acc[it] += h4[1]*w1;
      acc[it] += h4[2]*w2;
      acc[it] += h4[3]*w3;
    }
  }
  #pragma unroll
  for(int it=0;it<8;it++){
    ((f4*)(zx + (base + (size_t)(ig*8+it))*128))[q4] = acc[it];
  }
}

// ============ k_lstm v4: barrier-free serial recurrence + fused head ====
__global__ __launch_bounds__(256,2) void k_lstm(const float* __restrict__ zx,
    const float* __restrict__ wh,
    const float* __restrict__ w1, const float* __restrict__ b1,
    const float* __restrict__ w2, const float* __restrict__ b2,
    float* __restrict__ out){
  __shared__ float hsh[8*32];
  int tid = threadIdx.x;
  int r = tid>>5, c = tid&31;
  int row = blockIdx.x*8 + r;          // < 8000
  const float* zr = zx + (size_t)row*TT*128;
  float wr0[32], wr1[32], wr2[32], wr3[32];
  #pragma unroll
  for(int i=0;i<32;i++){
    wr0[i]=wh[i*128 + c];
    wr1[i]=wh[i*128 + 32 + c];
    wr2[i]=wh[i*128 + 64 + c];
    wr3[i]=wh[i*128 + 96 + c];
  }
  const f4* hrow4 = (const f4*)&hsh[r*32];
  float h=0.f, cs=0.f;
  float p0=zr[c], p1=zr[32+c], p2=zr[64+c], p3=zr[96+c];
  for(int t=0;t<TT;t++){
    float z0=p0, z1=p1, z2=p2, z3=p3;
    if(t+1<TT){
      const float* nz = zr + (size_t)(t+1)*128;
      p0=nz[c]; p1=nz[32+c]; p2=nz[64+c]; p3=nz[96+c];
    }
    hsh[r*32+c] = h;                   // same-wave visibility (lgkmcnt)
    #pragma unroll
    for(int i4=0;i4<8;i4++){
      f4 h4 = hrow4[i4];
      #pragma unroll
      for(int k=0;k<4;k++){
        int i = i4*4+k;
        z0 = fmaf(h4[k], wr0[i], z0);
        z1 = fmaf(h4[k], wr1[i], z1);
        z2 = fmaf(h4[k], wr2[i], z2);
        z3 = fmaf(h4[k], wr3[i], z3);
      }
    }
    float ig = sigmfast_(z0);
    float fg = sigmfast_(z1);
    float gg = tanhfast_(z2);
    float og = sigmfast_(z3);
    cs = fg*cs + ig*gg;
    h = og*tanhfast_(cs);
  }
  // head: t1 = silu(h@w1+b1); y = t1@w2+b2
  int b = row/NN, n = row%NN;
  hsh[r*32+c] = h;
  float t1 = b1[c];
  #pragma unroll
  for(int i4=0;i4<8;i4++){
    f4 h4 = hrow4[i4];
    #pragma unroll
    for(int k=0;k<4;k++) t1 = fmaf(h4[k], w1[(i4*4+k)*32+c], t1);
  }
  t1 = siluf_(t1);
  hsh[r*32+c] = t1;
  float y = (c<PREDN)? b2[c] : 0.f;
  #pragma unroll
  for(int i4=0;i4<8;i4++){
    f4 t4 = hrow4[i4];
    #pragma unroll
    for(int k=0;k<4;k++){
      if(c<PREDN) y = fmaf(t4[k], w2[(i4*4+k)*PREDN+c], y);
    }
  }
  if(c<PREDN) out[((size_t)b*PREDN + c)*NN + n] = y;
}

extern "C" void kernel_launch(void* const* d_in, const int* in_sizes, int n_in,
                              void* d_out, int out_size, void* d_ws, size_t ws_size,
                              hipStream_t stream) {
  const float* x       = (const float*)d_in[0];
  const float* xraw    = (const float*)d_in[1];
  const float* W       = (const float*)d_in[3];
  const int*   members = (const int*)d_in[4];
  const int*   centers = (const int*)d_in[5];
  const int*   offsets = (const int*)d_in[6];
  const float* ipw     = (const float*)d_in[7];
  const float* ipb     = (const float*)d_in[8];
  const float* cw      = (const float*)d_in[9];
  const float* cb      = (const float*)d_in[10];
  const float* wx      = (const float*)d_in[11];
  const float* wh      = (const float*)d_in[12];
  const float* lb      = (const float*)d_in[13];
  const float* w1      = (const float*)d_in[14];
  const float* b1      = (const float*)d_in[15];
  const float* w2      = (const float*)d_in[16];
  const float* b2      = (const float*)d_in[17];
  float* out = (float*)d_out;

  float* zx   = (float*)d_ws;                 // 24,576,000 floats
  float* h2g  = zx + 24576000;                // 6,144,000
  float* feat = h2g + 6144000;                // 128,000
  float* ms   = feat + 128000;                // 8,000
  float* Wd   = ms + 8000;                    // 8,000
  float* dvi  = Wd + 8000;                    // 8,000
  int* edge_nodes = (int*)(dvi + 8000);       // 21,000
  int* edge_cnt   = edge_nodes + 21000;       // 1,000
  int* node_off   = edge_cnt + 1000;          // 1,001
  int* node_deg   = node_off + 1001;          // 1,000
  int* cursor     = node_deg + 1000;          // 1,000
  int* node_edges = cursor + 1000;            // 21,000

  hipMemsetAsync(node_deg, 0, 2000*sizeof(int), stream);   // node_deg + cursor

  k_feat<<<250, 256, 0, stream>>>(xraw, feat);
  k_dedup<<<16, 64, 0, stream>>>(members, centers, offsets,
                                 edge_nodes, edge_cnt, node_deg);
  k_scan<<<1, 1024, 0, stream>>>(node_deg, node_off);
  k_fill<<<16, 64, 0, stream>>>(edge_nodes, edge_cnt, node_off,
                                cursor, node_edges);
  k_sim1<<<125, 256, 0, stream>>>(feat, members, centers, offsets, ms);
  k_sim2dv<<<BB, 1024, 0, stream>>>(ms, W, node_off, node_edges, Wd, dvi);
  k_slice<<<BB*TT*2, 1024, 0, stream>>>(x, ipw, ipb, dvi, Wd,
                                        edge_nodes, edge_cnt, node_off, node_edges,
                                        h2g);
  k_zx<<<3000, 256, 0, stream>>>(h2g, cw, cb, wx, lb, zx);
  k_lstm<<<(BB*NN)/8, 256, 0, stream>>>(zx, wh, w1, b1, w2, b2, out);
}